// Round 9
// baseline (10551.541 us; speedup 1.0000x reference)
//
#include <hip/hip_runtime.h>
#include <stdint.h>

// DecoderRNN R24: R23 base (8.77ms) + flag fan-in de-serialization:
//  - Each 32-producer counter (FADDI, same-address RMW serialized at LLC)
//    becomes a 32-SLOT LINE: producer stores step-tag t+1 to its own slot
//    (plain sc0sc1 dword, distinct addresses -> parallel at LLC).
//  - Consumer polls with tid0 ONLY (R21's multi-wave poll hotspot avoided),
//    reading the 128B line as 8 parallel dwordx4 per iteration + min-fold.
//  - role3 polls both h1-half lines in ONE 16-load batch (was 2 serial
//    dependent counter RTTs per poll iteration).
//  - role0 y-sum: pairwise tree (depth 5) instead of 31-deep serial chain.
// Everything else byte-identical to R23 (role1 eliminated, role2 x64 4-way
// K-split w/ slack-funded gh1, Wih1 hi-only, planar hi/lo h, drain->flag).
// mbox layout: per consumer line = 3 sub-lines x 32 ints (384B, 3 cache
// lines): [0]=h0 slots, [1]=h1-half-a / y slots, [2]=h1-half-b slots.

#define NWG 256
#define NT  256
#define TT  1024

typedef unsigned short ushort;
typedef unsigned int   uint;
typedef __attribute__((ext_vector_type(8))) short short8;
typedef __attribute__((ext_vector_type(4))) float f32x4;
typedef __attribute__((ext_vector_type(4))) uint  uint4v;

struct __align__(16) SmemR0 {
  ushort wpl[2][48*520];     // Whh0 hi/lo
  float  gictx[3*16*68];
  float  wcol[3][16];
  float  bhnN[16];
  float  prevS[64];          // [0..32) used
};
struct __align__(16) SmemR2 {
  ushort whh[2][48*520];     // Whh1 hi/lo (full precision, self-recurrence)
  ushort wih[48*520];        // Wih1 HI ONLY (critical path)
  float  xk[3][64][16];      // k-quarter combine: {R,Z,Ni,Nh} x4
  float  bsumR[16], bsumZ[16], binN[16], bhnN[16];
};
struct __align__(16) SmemR3 {
  ushort wpl[2][16*520];     // Wo1 block hi/lo
  float  xk[2][64][4];
  float  bo1v[16], wo2v[16];
};

__device__ __forceinline__ float frcp(float x){
#if __has_builtin(__builtin_amdgcn_rcpf)
  return __builtin_amdgcn_rcpf(x);
#else
  return 1.f/x;
#endif
}
__device__ __forceinline__ float sigm(float x){ return frcp(1.f + __expf(-x)); }
__device__ __forceinline__ float tanh_f(float x){
  return 1.f - 2.f*frcp(__expf(2.f*x) + 1.f);
}
__device__ __forceinline__ float bf2f(ushort h){ return __uint_as_float(((uint)h)<<16); }
__device__ __forceinline__ ushort bfrnd(float x){
  uint u = __float_as_uint(x);
  return (ushort)((u + 0x7fffu + ((u>>16)&1u)) >> 16);
}
#define SWP(p, v)  (void)__hip_atomic_exchange((uint*)(p), (uint)(v), __ATOMIC_RELAXED, __HIP_MEMORY_SCOPE_AGENT)
#define ALD1(p)    __hip_atomic_load((const uint*)(p), __ATOMIC_RELAXED, __HIP_MEMORY_SCOPE_AGENT)
#define ALDF(p)    __uint_as_float(ALD1(p))

__device__ __forceinline__ void gbar(int* slots, int* epoch, int w, int tid, int e){
  __syncthreads();
  if (tid == 0)
    __hip_atomic_store(&slots[w], e, __ATOMIC_RELEASE, __HIP_MEMORY_SCOPE_AGENT);
  if (w == 0 && tid < 64){
    for(;;){
      int m0 = __hip_atomic_load(&slots[tid*4+0], __ATOMIC_RELAXED, __HIP_MEMORY_SCOPE_AGENT);
      int m1 = __hip_atomic_load(&slots[tid*4+1], __ATOMIC_RELAXED, __HIP_MEMORY_SCOPE_AGENT);
      int m2 = __hip_atomic_load(&slots[tid*4+2], __ATOMIC_RELAXED, __HIP_MEMORY_SCOPE_AGENT);
      int m3 = __hip_atomic_load(&slots[tid*4+3], __ATOMIC_RELAXED, __HIP_MEMORY_SCOPE_AGENT);
      if (__all(min(min(m0,m1),min(m2,m3)) >= e)) break;
      __builtin_amdgcn_s_sleep(1);
    }
    if (tid == 0){
      __builtin_amdgcn_fence(__ATOMIC_ACQUIRE, "agent");
      __hip_atomic_store(epoch, e, __ATOMIC_RELEASE, __HIP_MEMORY_SCOPE_AGENT);
    }
  }
  if (tid == 0){
    while (__hip_atomic_load(epoch, __ATOMIC_RELAXED, __HIP_MEMORY_SCOPE_AGENT) < e)
      __builtin_amdgcn_s_sleep(1);
    __builtin_amdgcn_fence(__ATOMIC_ACQUIRE, "agent");
  }
  __syncthreads();
}

__device__ __forceinline__ void drain_sync(){
  __builtin_amdgcn_s_waitcnt(0);
  __syncthreads();
}

// coherent LLC-direct ops (sc0 sc1 = bypass L1+L2, coalesced)
#define LD1SCD(dst, addr) \
  asm volatile("global_load_dword %0, %1, off sc0 sc1" : "=v"(dst) : "v"(addr));
#define STSH(addr, val) \
  asm volatile("global_store_short %0, %1, off sc0 sc1" :: "v"(addr), "v"(val) : "memory");
#define STI(addr, val) \
  asm volatile("global_store_dword %0, %1, off sc0 sc1" :: "v"(addr), "v"(val) : "memory");
#define ST4SC(addr, val) \
  asm volatile("global_store_dwordx4 %0, %1, off sc0 sc1" :: "v"(addr), "v"(val) : "memory");
#define LD4A(DST, P, OFS) \
  asm volatile("global_load_dwordx4 %0, %1, off sc0 sc1" : "=v"(DST) : "v"((P) + (OFS)));
#define VMBAR4(a,b,c,d) \
  asm volatile("s_waitcnt vmcnt(0)" : "+v"(a),"+v"(b),"+v"(c),"+v"(d));
#define VMBAR8(a,b,c,d,e,f,g,h) \
  asm volatile("s_waitcnt vmcnt(0)" \
               : "+v"(a),"+v"(b),"+v"(c),"+v"(d),"+v"(e),"+v"(f),"+v"(g),"+v"(h));

__device__ __forceinline__ int min4i(uint4v a){
  return min(min((int)a.x,(int)a.y), min((int)a.z,(int)a.w));
}
// tid0 polls one 32-slot line via 8 parallel dwordx4; min-fold; syncthreads
__device__ __forceinline__ void waitline(const int* line, int target, int tid){
  if (tid == 0){
    const uint* p = (const uint*)line;
    for(;;){
      uint4v a0,a1,a2,a3,a4,a5,a6,a7;
      LD4A(a0,p,0)  LD4A(a1,p,4)  LD4A(a2,p,8)  LD4A(a3,p,12)
      LD4A(a4,p,16) LD4A(a5,p,20) LD4A(a6,p,24) LD4A(a7,p,28)
      VMBAR8(a0,a1,a2,a3,a4,a5,a6,a7)
      int m = min(min(min(min4i(a0),min4i(a1)),min(min4i(a2),min4i(a3))),
                  min(min(min4i(a4),min4i(a5)),min(min4i(a6),min4i(a7))));
      if (m >= target) break;
    }
  }
  __syncthreads();
}
// two lines in one parallel batch (role3's h1 halves)
__device__ __forceinline__ void waitline2(const int* la, const int* lb, int target, int tid){
  if (tid == 0){
    const uint* pa = (const uint*)la;
    const uint* pb = (const uint*)lb;
    for(;;){
      uint4v a0,a1,a2,a3,a4,a5,a6,a7;
      uint4v b0,b1,b2,b3,b4,b5,b6,b7;
      LD4A(a0,pa,0)  LD4A(a1,pa,4)  LD4A(a2,pa,8)  LD4A(a3,pa,12)
      LD4A(a4,pa,16) LD4A(a5,pa,20) LD4A(a6,pa,24) LD4A(a7,pa,28)
      LD4A(b0,pb,0)  LD4A(b1,pb,4)  LD4A(b2,pb,8)  LD4A(b3,pb,12)
      LD4A(b4,pb,16) LD4A(b5,pb,20) LD4A(b6,pb,24) LD4A(b7,pb,28)
      VMBAR8(a0,a1,a2,a3,a4,a5,a6,a7)
      VMBAR8(b0,b1,b2,b3,b4,b5,b6,b7)
      int ma = min(min(min(min4i(a0),min4i(a1)),min(min4i(a2),min4i(a3))),
                   min(min(min4i(a4),min4i(a5)),min(min4i(a6),min4i(a7))));
      int mb = min(min(min(min4i(b0),min4i(b1)),min(min4i(b2),min4i(b3))),
                   min(min(min4i(b4),min4i(b5)),min(min4i(b6),min4i(b7))));
      if (min(ma,mb) >= target) break;
    }
  }
  __syncthreads();
}

#define MFMA_ __builtin_amdgcn_mfma_f32_16x16x32_bf16

// ---------------- role0: full-K hi/lo (waves 0,1) ----------------
#define DECL_HILO(PH, PL) \
  uint4v ha0,ha1,ha2,ha3,ha4,ha5,ha6,ha7,ha8,ha9,ha10,ha11,ha12,ha13,ha14,ha15; \
  uint4v la0,la1,la2,la3,la4,la5,la6,la7,la8,la9,la10,la11,la12,la13,la14,la15; \
  LD4A(ha0,PH,aoffB+0*32) LD4A(ha1,PH,aoffB+1*32) LD4A(ha2,PH,aoffB+2*32) LD4A(ha3,PH,aoffB+3*32) \
  LD4A(ha4,PH,aoffB+4*32) LD4A(ha5,PH,aoffB+5*32) LD4A(ha6,PH,aoffB+6*32) LD4A(ha7,PH,aoffB+7*32) \
  LD4A(ha8,PH,aoffB+8*32) LD4A(ha9,PH,aoffB+9*32) LD4A(ha10,PH,aoffB+10*32) LD4A(ha11,PH,aoffB+11*32) \
  LD4A(ha12,PH,aoffB+12*32) LD4A(ha13,PH,aoffB+13*32) LD4A(ha14,PH,aoffB+14*32) LD4A(ha15,PH,aoffB+15*32) \
  LD4A(la0,PL,aoffB+0*32) LD4A(la1,PL,aoffB+1*32) LD4A(la2,PL,aoffB+2*32) LD4A(la3,PL,aoffB+3*32) \
  LD4A(la4,PL,aoffB+4*32) LD4A(la5,PL,aoffB+5*32) LD4A(la6,PL,aoffB+6*32) LD4A(la7,PL,aoffB+7*32) \
  LD4A(la8,PL,aoffB+8*32) LD4A(la9,PL,aoffB+9*32) LD4A(la10,PL,aoffB+10*32) LD4A(la11,PL,aoffB+11*32) \
  LD4A(la12,PL,aoffB+12*32) LD4A(la13,PL,aoffB+13*32) LD4A(la14,PL,aoffB+14*32) LD4A(la15,PL,aoffB+15*32) \
  VMBAR8(ha0,ha1,ha2,ha3,ha4,ha5,ha6,ha7) \
  VMBAR8(ha8,ha9,ha10,ha11,ha12,ha13,ha14,ha15) \
  VMBAR8(la0,la1,la2,la3,la4,la5,la6,la7) \
  VMBAR8(la8,la9,la10,la11,la12,la13,la14,la15)

#define MS3F(i) { \
  short8 AH_ = __builtin_bit_cast(short8, ha##i); \
  short8 AL_ = __builtin_bit_cast(short8, la##i); \
  const int ko_ = (i)*32 + q*8; \
  short8 bh_ = *(const short8*)(&S0.wpl[0][(col)*520 + ko_]); \
  short8 bl_ = *(const short8*)(&S0.wpl[1][(col)*520 + ko_]); \
  acc0 = MFMA_(AH_, bh_, acc0, 0,0,0); \
  acc0 = MFMA_(AL_, bh_, acc0, 0,0,0); \
  acc0 = MFMA_(AH_, bl_, acc0, 0,0,0); \
  bh_ = *(const short8*)(&S0.wpl[0][(16+col)*520 + ko_]); \
  bl_ = *(const short8*)(&S0.wpl[1][(16+col)*520 + ko_]); \
  acc1 = MFMA_(AH_, bh_, acc1, 0,0,0); \
  acc1 = MFMA_(AL_, bh_, acc1, 0,0,0); \
  acc1 = MFMA_(AH_, bl_, acc1, 0,0,0); \
  bh_ = *(const short8*)(&S0.wpl[0][(32+col)*520 + ko_]); \
  bl_ = *(const short8*)(&S0.wpl[1][(32+col)*520 + ko_]); \
  acc2 = MFMA_(AH_, bh_, acc2, 0,0,0); \
  acc2 = MFMA_(AL_, bh_, acc2, 0,0,0); \
  acc2 = MFMA_(AH_, bl_, acc2, 0,0,0); }

// ---------------- role2: gh1 full (hi/lo A,B) + gi (hi A, hi B) ----------
#define GH1(i) { \
  short8 AH_ = __builtin_bit_cast(short8, ha##i); \
  short8 AL_ = __builtin_bit_cast(short8, la##i); \
  const int ko_ = kq + (i)*32 + q*8; \
  short8 bh_ = *(const short8*)(&S2.whh[0][(col)*520 + ko_]); \
  short8 bl_ = *(const short8*)(&S2.whh[1][(col)*520 + ko_]); \
  aR = MFMA_(AH_, bh_, aR, 0,0,0); \
  aR = MFMA_(AL_, bh_, aR, 0,0,0); \
  aR = MFMA_(AH_, bl_, aR, 0,0,0); \
  bh_ = *(const short8*)(&S2.whh[0][(16+col)*520 + ko_]); \
  bl_ = *(const short8*)(&S2.whh[1][(16+col)*520 + ko_]); \
  aZ = MFMA_(AH_, bh_, aZ, 0,0,0); \
  aZ = MFMA_(AL_, bh_, aZ, 0,0,0); \
  aZ = MFMA_(AH_, bl_, aZ, 0,0,0); \
  bh_ = *(const short8*)(&S2.whh[0][(32+col)*520 + ko_]); \
  bl_ = *(const short8*)(&S2.whh[1][(32+col)*520 + ko_]); \
  aNh = MFMA_(AH_, bh_, aNh, 0,0,0); \
  aNh = MFMA_(AL_, bh_, aNh, 0,0,0); \
  aNh = MFMA_(AH_, bl_, aNh, 0,0,0); }

#define GI1(i) { \
  short8 AH_ = __builtin_bit_cast(short8, ga##i); \
  const int ko_ = kq + (i)*32 + q*8; \
  short8 bh_ = *(const short8*)(&S2.wih[(col)*520 + ko_]); \
  aR = MFMA_(AH_, bh_, aR, 0,0,0); \
  bh_ = *(const short8*)(&S2.wih[(16+col)*520 + ko_]); \
  aZ = MFMA_(AH_, bh_, aZ, 0,0,0); \
  bh_ = *(const short8*)(&S2.wih[(32+col)*520 + ko_]); \
  aNi = MFMA_(AH_, bh_, aNi, 0,0,0); }

// ---------------- role3: k-half hi A, hi/lo B -----------------------------
#define DECL_HI8(P) \
  uint4v ha0,ha1,ha2,ha3,ha4,ha5,ha6,ha7; \
  LD4A(ha0,P,aoff8+0*32) LD4A(ha1,P,aoff8+1*32) LD4A(ha2,P,aoff8+2*32) LD4A(ha3,P,aoff8+3*32) \
  LD4A(ha4,P,aoff8+4*32) LD4A(ha5,P,aoff8+5*32) LD4A(ha6,P,aoff8+6*32) LD4A(ha7,P,aoff8+7*32) \
  VMBAR8(ha0,ha1,ha2,ha3,ha4,ha5,ha6,ha7)

#define MS1H(i) { \
  short8 AH_ = __builtin_bit_cast(short8, ha##i); \
  const int ko_ = kb + (i)*32 + q*8; \
  short8 bh_ = *(const short8*)(&S3.wpl[0][(col)*520 + ko_]); \
  short8 bl_ = *(const short8*)(&S3.wpl[1][(col)*520 + ko_]); \
  acc0 = MFMA_(AH_, bh_, acc0, 0,0,0); \
  acc0 = MFMA_(AH_, bl_, acc0, 0,0,0); }

#define RUN16(M) M(0) M(1) M(2) M(3) M(4) M(5) M(6) M(7) \
                 M(8) M(9) M(10) M(11) M(12) M(13) M(14) M(15)
#define RUN8(M)  M(0) M(1) M(2) M(3) M(4) M(5) M(6) M(7)
#define RUN4(M)  M(0) M(1) M(2) M(3)

extern "C" __global__ void __launch_bounds__(NT, 1)
decoder_rnn(const float* __restrict__ ctx,   // [64][512]
            const float* __restrict__ Wih0,  // [1536][513] (row stride 513!)
            const float* __restrict__ Whh0,
            const float* __restrict__ bih0,
            const float* __restrict__ bhh0g,
            const float* __restrict__ Wih1,
            const float* __restrict__ Whh1,
            const float* __restrict__ bih1g,
            const float* __restrict__ bhh1g,
            const float* __restrict__ Wo1,
            const float* __restrict__ bo1g,
            const float* __restrict__ Wo2,
            const float* __restrict__ bo2g,
            float* __restrict__ out,         // [64*1024 y][65536 h_i]
            float* __restrict__ ws)
{
  extern __shared__ char smem_raw[];
  SmemR0& S0 = *reinterpret_cast<SmemR0*>(smem_raw);
  SmemR2& S2 = *reinterpret_cast<SmemR2*>(smem_raw);
  SmemR3& S3 = *reinterpret_cast<SmemR3*>(smem_raw);
  const int tid = threadIdx.x;
  const int wg  = blockIdx.x;

  ushort* hp  = (ushort*)ws;                 // h0hi[2]@0/32768, h0lo[2]@65536/
                                             // 98304, h1hi@131072, h1lo@163840
  float* yout = (float*)ws + 196608;         // 2 x 2048
  int*  ibase = (int*)((float*)ws + 200704);
  int* gslots = ibase;                       // [256] gbar
  int* epoch  = ibase + 256;
  int* mbox   = ibase + 512;                 // 256 lines x 96 ints (3 sublines)

  const float bo2v = bo2g[0];

  // ---------------- init (swaps -> LLC; once, off critical path) ----------
  for (int i = wg*NT + tid; i < 200704; i += NWG*NT)
    SWP((uint*)ws + i, 0u);
  if (wg == 0)
    for (int i = tid; i < 256*96; i += NT) SWP(mbox + i, 0);

  const int gid   = wg >> 7;                 // 2 independent 32-batch machines
  const int m     = wg & 127;
  const int bbase = 32*gid;
  int role, j, bh = 0;
  if (m < 32){ role = 0; j = m; }
  else if (m < 96){ role = 2; bh = (m - 32) >> 5; j = m & 31; }
  else { role = 3; j = m - 96; }

  if (role == 0){
    for (int i = tid; i < 48*512; i += NT){
      int r = i >> 9, k = i & 511;
      int g3 = r >> 4, n = r & 15;
      float wv = Whh0[(size_t)(g3*512 + 16*j + n)*512 + k];
      ushort hh = bfrnd(wv);
      S0.wpl[0][r*520 + k] = hh;
      S0.wpl[1][r*520 + k] = bfrnd(wv - bf2f(hh));
    }
    if (tid < 48){
      int g3 = tid >> 4, n = tid & 15;
      S0.wcol[g3][n] = Wih0[(size_t)(g3*512 + 16*j + n)*513 + 512];
    }
    if (tid < 16) S0.bhnN[tid] = bhh0g[2*512 + 16*j + tid];
    for (int idx = tid; idx < 1536; idx += NT){   // 48 rows x 32 local b
      int r = idx >> 5, bl = idx & 31;
      int g3 = r >> 4, n = r & 15;
      int grow = g3*512 + 16*j + n;
      const float* wr = Wih0 + (size_t)grow*513;
      const float* cx = ctx  + (size_t)(bbase + bl)*512;
      float s = bih0[grow];
      if (g3 < 2) s += bhh0g[grow];
      #pragma unroll 4
      for (int k = 0; k < 512; ++k) s += wr[k]*cx[k];
      S0.gictx[g3*1088 + n*68 + bl] = s;
    }
  } else if (role == 2){
    for (int i = tid; i < 48*512; i += NT){
      int r = i >> 9, k = i & 511;
      int g3 = r >> 4, n = r & 15;
      size_t row = (size_t)(g3*512 + 16*j + n)*512 + k;
      float wv = Whh1[row];
      ushort hh = bfrnd(wv);
      S2.whh[0][r*520 + k] = hh;
      S2.whh[1][r*520 + k] = bfrnd(wv - bf2f(hh));
      S2.wih[r*520 + k] = bfrnd(Wih1[row]);       // HI ONLY
    }
    if (tid < 16){
      int n = tid;
      S2.bsumR[n] = bih1g[16*j + n]       + bhh1g[16*j + n];
      S2.bsumZ[n] = bih1g[512 + 16*j + n] + bhh1g[512 + 16*j + n];
      S2.binN[n]  = bih1g[1024 + 16*j + n];
      S2.bhnN[n]  = bhh1g[1024 + 16*j + n];
    }
  } else {
    for (int i = tid; i < 16*512; i += NT){
      int r = i >> 9, k = i & 511;
      float wv = Wo1[(size_t)(16*j + r)*512 + k];
      ushort hh = bfrnd(wv);
      S3.wpl[0][r*520 + k] = hh;
      S3.wpl[1][r*520 + k] = bfrnd(wv - bf2f(hh));
    }
    if (tid < 16){ S3.bo1v[tid] = bo1g[16*j + tid]; S3.wo2v[tid] = Wo2[16*j + tid]; }
  }

  gbar(gslots, epoch, wg, tid, 1);

  int* myline = mbox + wg*96;
  const int gb = gid*128;

  const int v   = tid >> 6;
  const int l   = tid & 63;
  const int q   = l >> 4;
  const int col = l & 15;
  const int ng  = 16*j + col;

  if (role == 0){
    const int bblk  = v & 1;
    const int aoffB = (bbase + 16*bblk + col)*512 + q*8;
    const int b0wL  = 16*bblk + 4*q;
    float hc0 = 0.f, hc1 = 0.f, hc2 = 0.f, hc3 = 0.f;
    for (int t = 0; t < TT; ++t){
      const int r0 = t & 1, w0 = r0 ^ 1;
      waitline(myline + 0, t, tid);          // h0[t-1] complete (all 32 slots)
      const ushort* rH = hp + r0*32768;
      const ushort* rL = hp + 65536 + r0*32768;
      ushort*       wH = hp + w0*32768;
      ushort*       wL = hp + 65536 + w0*32768;
      f32x4 acc0={0,0,0,0}, acc1={0,0,0,0}, acc2={0,0,0,0};
      if (v < 2){
        DECL_HILO(rH, rL)
        RUN16(MS3F)
      }
      waitline(myline + 32, t, tid);         // y[t-1] partials at LLC
      if (tid < 32){
        float s = 0.f;
        if (t > 0){
          const float* yp = yout + ((t-1)&1)*2048 + bbase + tid;
          float vv[32];
          #pragma unroll
          for (int jj = 0; jj < 32; ++jj)
            LD1SCD(vv[jj], yp + jj*64)
          VMBAR8(vv[0],vv[1],vv[2],vv[3],vv[4],vv[5],vv[6],vv[7])
          VMBAR8(vv[8],vv[9],vv[10],vv[11],vv[12],vv[13],vv[14],vv[15])
          VMBAR8(vv[16],vv[17],vv[18],vv[19],vv[20],vv[21],vv[22],vv[23])
          VMBAR8(vv[24],vv[25],vv[26],vv[27],vv[28],vv[29],vv[30],vv[31])
          #pragma unroll
          for (int st = 16; st >= 1; st >>= 1)
            for (int k2 = 0; k2 < st; ++k2) vv[k2] += vv[k2 + st];
          s = vv[0];
        }
        float pv = fmaxf(s + bo2v, 0.f);
        S0.prevS[tid] = pv;
        if (j == 0 && t > 0) out[(size_t)(bbase + tid)*TT + (t-1)] = pv;
      }
      __syncthreads();
      if (v < 2){
        f32x4 pv4 = *(const f32x4*)&S0.prevS[b0wL];
        f32x4 gR = *(const f32x4*)&S0.gictx[0*1088 + col*68 + b0wL];
        f32x4 gZ = *(const f32x4*)&S0.gictx[1*1088 + col*68 + b0wL];
        f32x4 gN = *(const f32x4*)&S0.gictx[2*1088 + col*68 + b0wL];
        float wc0 = S0.wcol[0][col], wc1 = S0.wcol[1][col], wc2 = S0.wcol[2][col];
        float bhn = S0.bhnN[col];
        #define E0(i, HC) { \
          float rr = sigm(gR[i] + pv4[i]*wc0 + acc0[i]); \
          float zz = sigm(gZ[i] + pv4[i]*wc1 + acc1[i]); \
          float nn = tanh_f(gN[i] + pv4[i]*wc2 + rr*(acc2[i] + bhn)); \
          float h = (1.f-zz)*nn + zz*HC; \
          HC = h; \
          ushort hh_ = bfrnd(h); \
          uint hu_ = hh_, lu_ = bfrnd(h - bf2f(hh_)); \
          STSH(wH + (size_t)(bbase + b0wL + (i))*512 + ng, hu_) \
          STSH(wL + (size_t)(bbase + b0wL + (i))*512 + ng, lu_) }
        E0(0,hc0) E0(1,hc1) E0(2,hc2) E0(3,hc3)
        #undef E0
      }
      drain_sync();
      if (tid < 96)                          // h0 slot j -> role0 0..31 + role2 32..95
        STI(mbox + (gb + tid)*96 + j, t + 1)
    }
  } else if (role == 2){
    ushort* p1H = hp + 131072;
    ushort* p1L = hp + 163840;
    const int bb16  = bbase + 16*bh;
    const int kq    = v*128;                 // k-quarter per wave
    const int aoffA = (bb16 + col)*512 + kq + q*8;
    float hc0 = 0.f, hc1 = 0.f, hc2 = 0.f, hc3 = 0.f;   // wave0: batches 4q+i
    for (int t = 0; t < TT; ++t){
      const int w0 = (t & 1) ^ 1;
      // -------- phase A (slack-funded): gh1 = Whh1 @ h1[t-1], full prec ----
      waitline(myline + 32*(1 + bh), t, tid);  // own-half h1[t-1] complete
      f32x4 aR={0,0,0,0}, aZ={0,0,0,0}, aNi={0,0,0,0}, aNh={0,0,0,0};
      {
        uint4v ha0,ha1,ha2,ha3, la0,la1,la2,la3;
        LD4A(ha0, p1H, aoffA+0*32) LD4A(ha1, p1H, aoffA+1*32)
        LD4A(ha2, p1H, aoffA+2*32) LD4A(ha3, p1H, aoffA+3*32)
        LD4A(la0, p1L, aoffA+0*32) LD4A(la1, p1L, aoffA+1*32)
        LD4A(la2, p1L, aoffA+2*32) LD4A(la3, p1L, aoffA+3*32)
        VMBAR8(ha0,ha1,ha2,ha3,la0,la1,la2,la3)
        RUN4(GH1)
      }
      // -------- phase B (critical): gi = Wih1_hi @ h0hi[t] ----------------
      waitline(myline + 0, t + 1, tid);      // h0[t] complete
      {
        const ushort* rH = hp + w0*32768;
        uint4v ga0,ga1,ga2,ga3;
        LD4A(ga0, rH, aoffA+0*32) LD4A(ga1, rH, aoffA+1*32)
        LD4A(ga2, rH, aoffA+2*32) LD4A(ga3, rH, aoffA+3*32)
        VMBAR4(ga0,ga1,ga2,ga3)
        RUN4(GI1)
      }
      // -------- combine k-quarters, EW, store -----------------------------
      if (v >= 1){
        *(f32x4*)&S2.xk[v-1][l][0]  = aR;
        *(f32x4*)&S2.xk[v-1][l][4]  = aZ;
        *(f32x4*)&S2.xk[v-1][l][8]  = aNi;
        *(f32x4*)&S2.xk[v-1][l][12] = aNh;
      }
      __syncthreads();
      if (v == 0){
        #pragma unroll
        for (int w = 0; w < 3; ++w){
          aR  += *(const f32x4*)&S2.xk[w][l][0];
          aZ  += *(const f32x4*)&S2.xk[w][l][4];
          aNi += *(const f32x4*)&S2.xk[w][l][8];
          aNh += *(const f32x4*)&S2.xk[w][l][12];
        }
        float bsR = S2.bsumR[col], bsZ = S2.bsumZ[col];
        float biN = S2.binN[col],  bhN = S2.bhnN[col];
        #define E1(i, HC) { \
          float r1 = sigm(aR[i] + bsR); \
          float z1 = sigm(aZ[i] + bsZ); \
          float n1 = tanh_f(aNi[i] + biN + r1*(aNh[i] + bhN)); \
          float h = (1.f-z1)*n1 + z1*HC; \
          HC = h; \
          ushort hh_ = bfrnd(h); \
          uint hu_ = hh_, lu_ = bfrnd(h - bf2f(hh_)); \
          STSH(p1H + (size_t)(bb16 + 4*q + (i))*512 + ng, hu_) \
          STSH(p1L + (size_t)(bb16 + 4*q + (i))*512 + ng, lu_) }
        E1(0,hc0) E1(1,hc1) E1(2,hc2) E1(3,hc3)
        #undef E1
      }
      drain_sync();
      if (tid < 96)                          // h1 slot j -> role2 32..95 + role3 96..127
        STI(mbox + (gb + 32 + tid)*96 + 32*(1 + bh) + j, t + 1)
    }
  } else {
    const ushort* rH = hp + 131072;          // h1 hi plane ONLY (critical)
    const int bblk  = v & 1;
    const int kb    = (v >> 1)*256;
    const int aoff8 = (bbase + 16*bblk + col)*512 + kb + q*8;
    const int b0wL  = 16*bblk + 4*q;
    for (int t = 0; t < TT; ++t){
      waitline2(myline + 32, myline + 64, t + 1, tid);   // h1[t] both halves
      f32x4 acc0={0,0,0,0};
      {
        DECL_HI8(rH)
        RUN8(MS1H)
      }
      if (v >= 2)
        *(f32x4*)&S3.xk[bblk][l][0] = acc0;
      __syncthreads();
      if (v < 2){
        acc0 += *(const f32x4*)&S3.xk[bblk][l][0];
        float s0 = S3.wo2v[col]*fmaxf(acc0[0] + S3.bo1v[col], 0.f);
        float s1 = S3.wo2v[col]*fmaxf(acc0[1] + S3.bo1v[col], 0.f);
        float s2 = S3.wo2v[col]*fmaxf(acc0[2] + S3.bo1v[col], 0.f);
        float s3 = S3.wo2v[col]*fmaxf(acc0[3] + S3.bo1v[col], 0.f);
        #pragma unroll
        for (int d = 1; d < 16; d <<= 1){
          s0 += __shfl_xor(s0, d);
          s1 += __shfl_xor(s1, d);
          s2 += __shfl_xor(s2, d);
          s3 += __shfl_xor(s3, d);
        }
        if (col == 0){
          float* rp = yout + (t&1)*2048 + j*64 + bbase + b0wL;
          f32x4 sv = {s0, s1, s2, s3};
          ST4SC(rp, sv)
        }
      }
      drain_sync();
      if (tid < 32)                          // y slot j -> role0 lines
        STI(mbox + (gb + tid)*96 + 32 + j, t + 1)
    }
  }

  // ---------------- finale: one global release/acquire barrier ------------
  gbar(gslots, epoch, wg, tid, 2);
  if (wg == 0 && tid < 64){
    float s = 0.f;
    const float* yp = yout + 2048 + tid;     // parity of t=1023 is 1
    #pragma unroll
    for (int jj = 0; jj < 32; ++jj) s += ALDF(yp + jj*64);
    out[(size_t)tid*TT + 1023] = fmaxf(s + bo2v, 0.f);
  }
  {
    int g = wg*256 + tid;                    // 256 WGs x 256 thr = 65536
    if (g < 32768) out[65536 + g] = bf2f(hp[g]) + bf2f(hp[65536 + g]);
    else {
      int g2 = g - 32768;
      out[65536 + g] = bf2f(hp[131072 + g2]) + bf2f(hp[163840 + g2]);
    }
  }
}

extern "C" void kernel_launch(void* const* d_in, const int* in_sizes, int n_in,
                              void* d_out, int out_size, void* d_ws, size_t ws_size,
                              hipStream_t stream){
  const float* ctx   = (const float*)d_in[0];
  const float* Wih0  = (const float*)d_in[2];
  const float* Whh0  = (const float*)d_in[3];
  const float* bih0  = (const float*)d_in[4];
  const float* bhh0  = (const float*)d_in[5];
  const float* Wih1  = (const float*)d_in[6];
  const float* Whh1  = (const float*)d_in[7];
  const float* bih1  = (const float*)d_in[8];
  const float* bhh1  = (const float*)d_in[9];
  const float* Wo1   = (const float*)d_in[10];
  const float* bo1   = (const float*)d_in[11];
  const float* Wo2   = (const float*)d_in[12];
  const float* bo2   = (const float*)d_in[13];

  (void)in_sizes; (void)n_in; (void)out_size; (void)ws_size;

  const int smem_sz = (int)sizeof(SmemR2);   // largest overlay (162,304 B)
  (void)hipFuncSetAttribute((const void*)decoder_rnn,
                            hipFuncAttributeMaxDynamicSharedMemorySize,
                            smem_sz);

  decoder_rnn<<<NWG, NT, smem_sz, stream>>>(
      ctx, Wih0, Whh0, bih0, bhh0, Wih1, Whh1, bih1, bhh1,
      Wo1, bo1, Wo2, bo2, (float*)d_out, (float*)d_ws);
}

// Round 10
// 8978.267 us; speedup vs baseline: 1.1752x; 1.1752x over previous
//
#include <hip/hip_runtime.h>
#include <stdint.h>

// DecoderRNN R25: R23 base (8.77ms, proven) + GROUPED flag counters.
//  R24 regressed (+1.8ms): slot-line polling cost 8 dwordx4/iteration per
//  poller (vs R23's 1 dword) -> LLC poll-traffic hotspot (same family as
//  R21). Lesson: consumer poll request count is the most sensitive knob.
//  R25 keeps poll cost IDENTICAL to R23 (one 16B request per iteration)
//  while cutting producer RMW fan-in 4x: each 32-producer counter becomes
//  4 group counters (producers grouped by j>>3, 8 same-address RMWs each)
//  laid out in ONE 16B span, polled with a single dwordx4 + min-fold.
//  role3 polls both h1-half quads with two PARALLEL dwordx4 (R23: serial).
//  + R24's safe piece: pairwise tree for role0's 32-partial y-sum.
// Line layout (128B per consumer WG): dwords [0..3]=h0 groups,
//  [4..7]=h1 half-a groups, [8..11]=h1 half-b groups, [12..15]=y groups.
// Targets: counters advance +8/step -> poll >= 8t (or 8(t+1)).
// Everything else byte-identical to R23 (role1 eliminated, role2 x64 4-way
// K-split w/ slack-funded gh1, Wih1 hi-only, planar hi/lo h, drain->flag).

#define NWG 256
#define NT  256
#define TT  1024

typedef unsigned short ushort;
typedef unsigned int   uint;
typedef __attribute__((ext_vector_type(8))) short short8;
typedef __attribute__((ext_vector_type(4))) float f32x4;
typedef __attribute__((ext_vector_type(4))) uint  uint4v;

struct __align__(16) SmemR0 {
  ushort wpl[2][48*520];     // Whh0 hi/lo
  float  gictx[3*16*68];
  float  wcol[3][16];
  float  bhnN[16];
  float  prevS[64];          // [0..32) used
};
struct __align__(16) SmemR2 {
  ushort whh[2][48*520];     // Whh1 hi/lo (full precision, self-recurrence)
  ushort wih[48*520];        // Wih1 HI ONLY (critical path)
  float  xk[3][64][16];      // k-quarter combine: {R,Z,Ni,Nh} x4
  float  bsumR[16], bsumZ[16], binN[16], bhnN[16];
};
struct __align__(16) SmemR3 {
  ushort wpl[2][16*520];     // Wo1 block hi/lo
  float  xk[2][64][4];
  float  bo1v[16], wo2v[16];
};

__device__ __forceinline__ float frcp(float x){
#if __has_builtin(__builtin_amdgcn_rcpf)
  return __builtin_amdgcn_rcpf(x);
#else
  return 1.f/x;
#endif
}
__device__ __forceinline__ float sigm(float x){ return frcp(1.f + __expf(-x)); }
__device__ __forceinline__ float tanh_f(float x){
  return 1.f - 2.f*frcp(__expf(2.f*x) + 1.f);
}
__device__ __forceinline__ float bf2f(ushort h){ return __uint_as_float(((uint)h)<<16); }
__device__ __forceinline__ ushort bfrnd(float x){
  uint u = __float_as_uint(x);
  return (ushort)((u + 0x7fffu + ((u>>16)&1u)) >> 16);
}
#define SWP(p, v)  (void)__hip_atomic_exchange((uint*)(p), (uint)(v), __ATOMIC_RELAXED, __HIP_MEMORY_SCOPE_AGENT)
#define ALD1(p)    __hip_atomic_load((const uint*)(p), __ATOMIC_RELAXED, __HIP_MEMORY_SCOPE_AGENT)
#define ALDF(p)    __uint_as_float(ALD1(p))
#define FADDI(p)   (void)__hip_atomic_fetch_add((p), 1, __ATOMIC_RELAXED, __HIP_MEMORY_SCOPE_AGENT)

__device__ __forceinline__ void gbar(int* slots, int* epoch, int w, int tid, int e){
  __syncthreads();
  if (tid == 0)
    __hip_atomic_store(&slots[w], e, __ATOMIC_RELEASE, __HIP_MEMORY_SCOPE_AGENT);
  if (w == 0 && tid < 64){
    for(;;){
      int m0 = __hip_atomic_load(&slots[tid*4+0], __ATOMIC_RELAXED, __HIP_MEMORY_SCOPE_AGENT);
      int m1 = __hip_atomic_load(&slots[tid*4+1], __ATOMIC_RELAXED, __HIP_MEMORY_SCOPE_AGENT);
      int m2 = __hip_atomic_load(&slots[tid*4+2], __ATOMIC_RELAXED, __HIP_MEMORY_SCOPE_AGENT);
      int m3 = __hip_atomic_load(&slots[tid*4+3], __ATOMIC_RELAXED, __HIP_MEMORY_SCOPE_AGENT);
      if (__all(min(min(m0,m1),min(m2,m3)) >= e)) break;
      __builtin_amdgcn_s_sleep(1);
    }
    if (tid == 0){
      __builtin_amdgcn_fence(__ATOMIC_ACQUIRE, "agent");
      __hip_atomic_store(epoch, e, __ATOMIC_RELEASE, __HIP_MEMORY_SCOPE_AGENT);
    }
  }
  if (tid == 0){
    while (__hip_atomic_load(epoch, __ATOMIC_RELAXED, __HIP_MEMORY_SCOPE_AGENT) < e)
      __builtin_amdgcn_s_sleep(1);
    __builtin_amdgcn_fence(__ATOMIC_ACQUIRE, "agent");
  }
  __syncthreads();
}

__device__ __forceinline__ void drain_sync(){
  __builtin_amdgcn_s_waitcnt(0);
  __syncthreads();
}

// coherent LLC-direct ops (sc0 sc1 = bypass L1+L2, coalesced)
#define LD1SCD(dst, addr) \
  asm volatile("global_load_dword %0, %1, off sc0 sc1" : "=v"(dst) : "v"(addr));
#define STSH(addr, val) \
  asm volatile("global_store_short %0, %1, off sc0 sc1" :: "v"(addr), "v"(val) : "memory");
#define ST4SC(addr, val) \
  asm volatile("global_store_dwordx4 %0, %1, off sc0 sc1" :: "v"(addr), "v"(val) : "memory");
#define LD4A(DST, P, OFS) \
  asm volatile("global_load_dwordx4 %0, %1, off sc0 sc1" : "=v"(DST) : "v"((P) + (OFS)));
#define VMBAR1(a)   asm volatile("s_waitcnt vmcnt(0)" : "+v"(a));
#define VMBAR2(a,b) asm volatile("s_waitcnt vmcnt(0)" : "+v"(a),"+v"(b));
#define VMBAR4(a,b,c,d) \
  asm volatile("s_waitcnt vmcnt(0)" : "+v"(a),"+v"(b),"+v"(c),"+v"(d));
#define VMBAR8(a,b,c,d,e,f,g,h) \
  asm volatile("s_waitcnt vmcnt(0)" \
               : "+v"(a),"+v"(b),"+v"(c),"+v"(d),"+v"(e),"+v"(f),"+v"(g),"+v"(h));

__device__ __forceinline__ int min4i(uint4v a){
  return min(min((int)a.x,(int)a.y), min((int)a.z,(int)a.w));
}
// tid0 polls 4 group counters in ONE dwordx4 (one LLC request/iteration,
// same cost as R23's single-dword counter poll)
__device__ __forceinline__ void waitq(const int* quad, int target, int tid){
  if (tid == 0){
    const uint* p = (const uint*)quad;
    for(;;){
      uint4v a;
      LD4A(a, p, 0)
      VMBAR1(a)
      if (min4i(a) >= target) break;
    }
  }
  __syncthreads();
}
// two quads polled in one parallel batch (role3's h1 halves)
__device__ __forceinline__ void waitq2(const int* qa, const int* qb, int target, int tid){
  if (tid == 0){
    const uint* pa = (const uint*)qa;
    const uint* pb = (const uint*)qb;
    for(;;){
      uint4v a, b;
      LD4A(a, pa, 0)
      LD4A(b, pb, 0)
      VMBAR2(a, b)
      if (min(min4i(a), min4i(b)) >= target) break;
    }
  }
  __syncthreads();
}

#define MFMA_ __builtin_amdgcn_mfma_f32_16x16x32_bf16

// ---------------- role0: full-K hi/lo (waves 0,1) ----------------
#define DECL_HILO(PH, PL) \
  uint4v ha0,ha1,ha2,ha3,ha4,ha5,ha6,ha7,ha8,ha9,ha10,ha11,ha12,ha13,ha14,ha15; \
  uint4v la0,la1,la2,la3,la4,la5,la6,la7,la8,la9,la10,la11,la12,la13,la14,la15; \
  LD4A(ha0,PH,aoffB+0*32) LD4A(ha1,PH,aoffB+1*32) LD4A(ha2,PH,aoffB+2*32) LD4A(ha3,PH,aoffB+3*32) \
  LD4A(ha4,PH,aoffB+4*32) LD4A(ha5,PH,aoffB+5*32) LD4A(ha6,PH,aoffB+6*32) LD4A(ha7,PH,aoffB+7*32) \
  LD4A(ha8,PH,aoffB+8*32) LD4A(ha9,PH,aoffB+9*32) LD4A(ha10,PH,aoffB+10*32) LD4A(ha11,PH,aoffB+11*32) \
  LD4A(ha12,PH,aoffB+12*32) LD4A(ha13,PH,aoffB+13*32) LD4A(ha14,PH,aoffB+14*32) LD4A(ha15,PH,aoffB+15*32) \
  LD4A(la0,PL,aoffB+0*32) LD4A(la1,PL,aoffB+1*32) LD4A(la2,PL,aoffB+2*32) LD4A(la3,PL,aoffB+3*32) \
  LD4A(la4,PL,aoffB+4*32) LD4A(la5,PL,aoffB+5*32) LD4A(la6,PL,aoffB+6*32) LD4A(la7,PL,aoffB+7*32) \
  LD4A(la8,PL,aoffB+8*32) LD4A(la9,PL,aoffB+9*32) LD4A(la10,PL,aoffB+10*32) LD4A(la11,PL,aoffB+11*32) \
  LD4A(la12,PL,aoffB+12*32) LD4A(la13,PL,aoffB+13*32) LD4A(la14,PL,aoffB+14*32) LD4A(la15,PL,aoffB+15*32) \
  VMBAR8(ha0,ha1,ha2,ha3,ha4,ha5,ha6,ha7) \
  VMBAR8(ha8,ha9,ha10,ha11,ha12,ha13,ha14,ha15) \
  VMBAR8(la0,la1,la2,la3,la4,la5,la6,la7) \
  VMBAR8(la8,la9,la10,la11,la12,la13,la14,la15)

#define MS3F(i) { \
  short8 AH_ = __builtin_bit_cast(short8, ha##i); \
  short8 AL_ = __builtin_bit_cast(short8, la##i); \
  const int ko_ = (i)*32 + q*8; \
  short8 bh_ = *(const short8*)(&S0.wpl[0][(col)*520 + ko_]); \
  short8 bl_ = *(const short8*)(&S0.wpl[1][(col)*520 + ko_]); \
  acc0 = MFMA_(AH_, bh_, acc0, 0,0,0); \
  acc0 = MFMA_(AL_, bh_, acc0, 0,0,0); \
  acc0 = MFMA_(AH_, bl_, acc0, 0,0,0); \
  bh_ = *(const short8*)(&S0.wpl[0][(16+col)*520 + ko_]); \
  bl_ = *(const short8*)(&S0.wpl[1][(16+col)*520 + ko_]); \
  acc1 = MFMA_(AH_, bh_, acc1, 0,0,0); \
  acc1 = MFMA_(AL_, bh_, acc1, 0,0,0); \
  acc1 = MFMA_(AH_, bl_, acc1, 0,0,0); \
  bh_ = *(const short8*)(&S0.wpl[0][(32+col)*520 + ko_]); \
  bl_ = *(const short8*)(&S0.wpl[1][(32+col)*520 + ko_]); \
  acc2 = MFMA_(AH_, bh_, acc2, 0,0,0); \
  acc2 = MFMA_(AL_, bh_, acc2, 0,0,0); \
  acc2 = MFMA_(AH_, bl_, acc2, 0,0,0); }

// ---------------- role2: gh1 full (hi/lo A,B) + gi (hi A, hi B) ----------
#define GH1(i) { \
  short8 AH_ = __builtin_bit_cast(short8, ha##i); \
  short8 AL_ = __builtin_bit_cast(short8, la##i); \
  const int ko_ = kq + (i)*32 + q*8; \
  short8 bh_ = *(const short8*)(&S2.whh[0][(col)*520 + ko_]); \
  short8 bl_ = *(const short8*)(&S2.whh[1][(col)*520 + ko_]); \
  aR = MFMA_(AH_, bh_, aR, 0,0,0); \
  aR = MFMA_(AL_, bh_, aR, 0,0,0); \
  aR = MFMA_(AH_, bl_, aR, 0,0,0); \
  bh_ = *(const short8*)(&S2.whh[0][(16+col)*520 + ko_]); \
  bl_ = *(const short8*)(&S2.whh[1][(16+col)*520 + ko_]); \
  aZ = MFMA_(AH_, bh_, aZ, 0,0,0); \
  aZ = MFMA_(AL_, bh_, aZ, 0,0,0); \
  aZ = MFMA_(AH_, bl_, aZ, 0,0,0); \
  bh_ = *(const short8*)(&S2.whh[0][(32+col)*520 + ko_]); \
  bl_ = *(const short8*)(&S2.whh[1][(32+col)*520 + ko_]); \
  aNh = MFMA_(AH_, bh_, aNh, 0,0,0); \
  aNh = MFMA_(AL_, bh_, aNh, 0,0,0); \
  aNh = MFMA_(AH_, bl_, aNh, 0,0,0); }

#define GI1(i) { \
  short8 AH_ = __builtin_bit_cast(short8, ga##i); \
  const int ko_ = kq + (i)*32 + q*8; \
  short8 bh_ = *(const short8*)(&S2.wih[(col)*520 + ko_]); \
  aR = MFMA_(AH_, bh_, aR, 0,0,0); \
  bh_ = *(const short8*)(&S2.wih[(16+col)*520 + ko_]); \
  aZ = MFMA_(AH_, bh_, aZ, 0,0,0); \
  bh_ = *(const short8*)(&S2.wih[(32+col)*520 + ko_]); \
  aNi = MFMA_(AH_, bh_, aNi, 0,0,0); }

// ---------------- role3: k-half hi A, hi/lo B -----------------------------
#define DECL_HI8(P) \
  uint4v ha0,ha1,ha2,ha3,ha4,ha5,ha6,ha7; \
  LD4A(ha0,P,aoff8+0*32) LD4A(ha1,P,aoff8+1*32) LD4A(ha2,P,aoff8+2*32) LD4A(ha3,P,aoff8+3*32) \
  LD4A(ha4,P,aoff8+4*32) LD4A(ha5,P,aoff8+5*32) LD4A(ha6,P,aoff8+6*32) LD4A(ha7,P,aoff8+7*32) \
  VMBAR8(ha0,ha1,ha2,ha3,ha4,ha5,ha6,ha7)

#define MS1H(i) { \
  short8 AH_ = __builtin_bit_cast(short8, ha##i); \
  const int ko_ = kb + (i)*32 + q*8; \
  short8 bh_ = *(const short8*)(&S3.wpl[0][(col)*520 + ko_]); \
  short8 bl_ = *(const short8*)(&S3.wpl[1][(col)*520 + ko_]); \
  acc0 = MFMA_(AH_, bh_, acc0, 0,0,0); \
  acc0 = MFMA_(AH_, bl_, acc0, 0,0,0); }

#define RUN16(M) M(0) M(1) M(2) M(3) M(4) M(5) M(6) M(7) \
                 M(8) M(9) M(10) M(11) M(12) M(13) M(14) M(15)
#define RUN8(M)  M(0) M(1) M(2) M(3) M(4) M(5) M(6) M(7)
#define RUN4(M)  M(0) M(1) M(2) M(3)

extern "C" __global__ void __launch_bounds__(NT, 1)
decoder_rnn(const float* __restrict__ ctx,   // [64][512]
            const float* __restrict__ Wih0,  // [1536][513] (row stride 513!)
            const float* __restrict__ Whh0,
            const float* __restrict__ bih0,
            const float* __restrict__ bhh0g,
            const float* __restrict__ Wih1,
            const float* __restrict__ Whh1,
            const float* __restrict__ bih1g,
            const float* __restrict__ bhh1g,
            const float* __restrict__ Wo1,
            const float* __restrict__ bo1g,
            const float* __restrict__ Wo2,
            const float* __restrict__ bo2g,
            float* __restrict__ out,         // [64*1024 y][65536 h_i]
            float* __restrict__ ws)
{
  extern __shared__ char smem_raw[];
  SmemR0& S0 = *reinterpret_cast<SmemR0*>(smem_raw);
  SmemR2& S2 = *reinterpret_cast<SmemR2*>(smem_raw);
  SmemR3& S3 = *reinterpret_cast<SmemR3*>(smem_raw);
  const int tid = threadIdx.x;
  const int wg  = blockIdx.x;

  ushort* hp  = (ushort*)ws;                 // h0hi[2]@0/32768, h0lo[2]@65536/
                                             // 98304, h1hi@131072, h1lo@163840
  float* yout = (float*)ws + 196608;         // 2 x 2048
  int*  ibase = (int*)((float*)ws + 200704);
  int* gslots = ibase;                       // [256] gbar
  int* epoch  = ibase + 256;
  int* mbox   = ibase + 512;                 // 256 lines x 32 ints
                                             // dwords: [0..3]=h0 grp,
                                             // [4..7]=h1a grp, [8..11]=h1b grp,
                                             // [12..15]=y grp

  const float bo2v = bo2g[0];

  // ---------------- init (swaps -> LLC; once, off critical path) ----------
  for (int i = wg*NT + tid; i < 200704; i += NWG*NT)
    SWP((uint*)ws + i, 0u);
  if (wg == 0)
    for (int i = tid; i < 256*32; i += NT) SWP(mbox + i, 0);

  const int gid   = wg >> 7;                 // 2 independent 32-batch machines
  const int m     = wg & 127;
  const int bbase = 32*gid;
  int role, j, bh = 0;
  if (m < 32){ role = 0; j = m; }
  else if (m < 96){ role = 2; bh = (m - 32) >> 5; j = m & 31; }
  else { role = 3; j = m - 96; }
  const int grp = j >> 3;                    // producer flag group (0..3)

  if (role == 0){
    for (int i = tid; i < 48*512; i += NT){
      int r = i >> 9, k = i & 511;
      int g3 = r >> 4, n = r & 15;
      float wv = Whh0[(size_t)(g3*512 + 16*j + n)*512 + k];
      ushort hh = bfrnd(wv);
      S0.wpl[0][r*520 + k] = hh;
      S0.wpl[1][r*520 + k] = bfrnd(wv - bf2f(hh));
    }
    if (tid < 48){
      int g3 = tid >> 4, n = tid & 15;
      S0.wcol[g3][n] = Wih0[(size_t)(g3*512 + 16*j + n)*513 + 512];
    }
    if (tid < 16) S0.bhnN[tid] = bhh0g[2*512 + 16*j + tid];
    for (int idx = tid; idx < 1536; idx += NT){   // 48 rows x 32 local b
      int r = idx >> 5, bl = idx & 31;
      int g3 = r >> 4, n = r & 15;
      int grow = g3*512 + 16*j + n;
      const float* wr = Wih0 + (size_t)grow*513;
      const float* cx = ctx  + (size_t)(bbase + bl)*512;
      float s = bih0[grow];
      if (g3 < 2) s += bhh0g[grow];
      #pragma unroll 4
      for (int k = 0; k < 512; ++k) s += wr[k]*cx[k];
      S0.gictx[g3*1088 + n*68 + bl] = s;
    }
  } else if (role == 2){
    for (int i = tid; i < 48*512; i += NT){
      int r = i >> 9, k = i & 511;
      int g3 = r >> 4, n = r & 15;
      size_t row = (size_t)(g3*512 + 16*j + n)*512 + k;
      float wv = Whh1[row];
      ushort hh = bfrnd(wv);
      S2.whh[0][r*520 + k] = hh;
      S2.whh[1][r*520 + k] = bfrnd(wv - bf2f(hh));
      S2.wih[r*520 + k] = bfrnd(Wih1[row]);       // HI ONLY
    }
    if (tid < 16){
      int n = tid;
      S2.bsumR[n] = bih1g[16*j + n]       + bhh1g[16*j + n];
      S2.bsumZ[n] = bih1g[512 + 16*j + n] + bhh1g[512 + 16*j + n];
      S2.binN[n]  = bih1g[1024 + 16*j + n];
      S2.bhnN[n]  = bhh1g[1024 + 16*j + n];
    }
  } else {
    for (int i = tid; i < 16*512; i += NT){
      int r = i >> 9, k = i & 511;
      float wv = Wo1[(size_t)(16*j + r)*512 + k];
      ushort hh = bfrnd(wv);
      S3.wpl[0][r*520 + k] = hh;
      S3.wpl[1][r*520 + k] = bfrnd(wv - bf2f(hh));
    }
    if (tid < 16){ S3.bo1v[tid] = bo1g[16*j + tid]; S3.wo2v[tid] = Wo2[16*j + tid]; }
  }

  gbar(gslots, epoch, wg, tid, 1);

  int* myline = mbox + wg*32;
  const int gb = gid*128;

  const int v   = tid >> 6;
  const int l   = tid & 63;
  const int q   = l >> 4;
  const int col = l & 15;
  const int ng  = 16*j + col;

  if (role == 0){
    const int bblk  = v & 1;
    const int aoffB = (bbase + 16*bblk + col)*512 + q*8;
    const int b0wL  = 16*bblk + 4*q;
    float hc0 = 0.f, hc1 = 0.f, hc2 = 0.f, hc3 = 0.f;
    for (int t = 0; t < TT; ++t){
      const int r0 = t & 1, w0 = r0 ^ 1;
      waitq(myline + 0, 8*t, tid);           // h0[t-1] complete (4 groups)
      const ushort* rH = hp + r0*32768;
      const ushort* rL = hp + 65536 + r0*32768;
      ushort*       wH = hp + w0*32768;
      ushort*       wL = hp + 65536 + w0*32768;
      f32x4 acc0={0,0,0,0}, acc1={0,0,0,0}, acc2={0,0,0,0};
      if (v < 2){
        DECL_HILO(rH, rL)
        RUN16(MS3F)
      }
      waitq(myline + 12, 8*t, tid);          // y[t-1] partials at LLC
      if (tid < 32){
        float s = 0.f;
        if (t > 0){
          const float* yp = yout + ((t-1)&1)*2048 + bbase + tid;
          float vv[32];
          #pragma unroll
          for (int jj = 0; jj < 32; ++jj)
            LD1SCD(vv[jj], yp + jj*64)
          VMBAR8(vv[0],vv[1],vv[2],vv[3],vv[4],vv[5],vv[6],vv[7])
          VMBAR8(vv[8],vv[9],vv[10],vv[11],vv[12],vv[13],vv[14],vv[15])
          VMBAR8(vv[16],vv[17],vv[18],vv[19],vv[20],vv[21],vv[22],vv[23])
          VMBAR8(vv[24],vv[25],vv[26],vv[27],vv[28],vv[29],vv[30],vv[31])
          #pragma unroll
          for (int st = 16; st >= 1; st >>= 1)
            for (int k2 = 0; k2 < st; ++k2) vv[k2] += vv[k2 + st];
          s = vv[0];
        }
        float pv = fmaxf(s + bo2v, 0.f);
        S0.prevS[tid] = pv;
        if (j == 0 && t > 0) out[(size_t)(bbase + tid)*TT + (t-1)] = pv;
      }
      __syncthreads();
      if (v < 2){
        f32x4 pv4 = *(const f32x4*)&S0.prevS[b0wL];
        f32x4 gR = *(const f32x4*)&S0.gictx[0*1088 + col*68 + b0wL];
        f32x4 gZ = *(const f32x4*)&S0.gictx[1*1088 + col*68 + b0wL];
        f32x4 gN = *(const f32x4*)&S0.gictx[2*1088 + col*68 + b0wL];
        float wc0 = S0.wcol[0][col], wc1 = S0.wcol[1][col], wc2 = S0.wcol[2][col];
        float bhn = S0.bhnN[col];
        #define E0(i, HC) { \
          float rr = sigm(gR[i] + pv4[i]*wc0 + acc0[i]); \
          float zz = sigm(gZ[i] + pv4[i]*wc1 + acc1[i]); \
          float nn = tanh_f(gN[i] + pv4[i]*wc2 + rr*(acc2[i] + bhn)); \
          float h = (1.f-zz)*nn + zz*HC; \
          HC = h; \
          ushort hh_ = bfrnd(h); \
          uint hu_ = hh_, lu_ = bfrnd(h - bf2f(hh_)); \
          STSH(wH + (size_t)(bbase + b0wL + (i))*512 + ng, hu_) \
          STSH(wL + (size_t)(bbase + b0wL + (i))*512 + ng, lu_) }
        E0(0,hc0) E0(1,hc1) E0(2,hc2) E0(3,hc3)
        #undef E0
      }
      drain_sync();
      if (tid < 96)                          // h0 group -> role0 0..31 + role2 32..95
        FADDI(mbox + (gb + tid)*32 + grp);
    }
  } else if (role == 2){
    ushort* p1H = hp + 131072;
    ushort* p1L = hp + 163840;
    const int bb16  = bbase + 16*bh;
    const int kq    = v*128;                 // k-quarter per wave
    const int aoffA = (bb16 + col)*512 + kq + q*8;
    float hc0 = 0.f, hc1 = 0.f, hc2 = 0.f, hc3 = 0.f;   // wave0: batches 4q+i
    for (int t = 0; t < TT; ++t){
      const int w0 = (t & 1) ^ 1;
      // -------- phase A (slack-funded): gh1 = Whh1 @ h1[t-1], full prec ----
      waitq(myline + 4 + 4*bh, 8*t, tid);    // own-half h1[t-1] complete
      f32x4 aR={0,0,0,0}, aZ={0,0,0,0}, aNi={0,0,0,0}, aNh={0,0,0,0};
      {
        uint4v ha0,ha1,ha2,ha3, la0,la1,la2,la3;
        LD4A(ha0, p1H, aoffA+0*32) LD4A(ha1, p1H, aoffA+1*32)
        LD4A(ha2, p1H, aoffA+2*32) LD4A(ha3, p1H, aoffA+3*32)
        LD4A(la0, p1L, aoffA+0*32) LD4A(la1, p1L, aoffA+1*32)
        LD4A(la2, p1L, aoffA+2*32) LD4A(la3, p1L, aoffA+3*32)
        VMBAR8(ha0,ha1,ha2,ha3,la0,la1,la2,la3)
        RUN4(GH1)
      }
      // -------- phase B (critical): gi = Wih1_hi @ h0hi[t] ----------------
      waitq(myline + 0, 8*(t+1), tid);       // h0[t] complete
      {
        const ushort* rH = hp + w0*32768;
        uint4v ga0,ga1,ga2,ga3;
        LD4A(ga0, rH, aoffA+0*32) LD4A(ga1, rH, aoffA+1*32)
        LD4A(ga2, rH, aoffA+2*32) LD4A(ga3, rH, aoffA+3*32)
        VMBAR4(ga0,ga1,ga2,ga3)
        RUN4(GI1)
      }
      // -------- combine k-quarters, EW, store -----------------------------
      if (v >= 1){
        *(f32x4*)&S2.xk[v-1][l][0]  = aR;
        *(f32x4*)&S2.xk[v-1][l][4]  = aZ;
        *(f32x4*)&S2.xk[v-1][l][8]  = aNi;
        *(f32x4*)&S2.xk[v-1][l][12] = aNh;
      }
      __syncthreads();
      if (v == 0){
        #pragma unroll
        for (int w = 0; w < 3; ++w){
          aR  += *(const f32x4*)&S2.xk[w][l][0];
          aZ  += *(const f32x4*)&S2.xk[w][l][4];
          aNi += *(const f32x4*)&S2.xk[w][l][8];
          aNh += *(const f32x4*)&S2.xk[w][l][12];
        }
        float bsR = S2.bsumR[col], bsZ = S2.bsumZ[col];
        float biN = S2.binN[col],  bhN = S2.bhnN[col];
        #define E1(i, HC) { \
          float r1 = sigm(aR[i] + bsR); \
          float z1 = sigm(aZ[i] + bsZ); \
          float n1 = tanh_f(aNi[i] + biN + r1*(aNh[i] + bhN)); \
          float h = (1.f-z1)*n1 + z1*HC; \
          HC = h; \
          ushort hh_ = bfrnd(h); \
          uint hu_ = hh_, lu_ = bfrnd(h - bf2f(hh_)); \
          STSH(p1H + (size_t)(bb16 + 4*q + (i))*512 + ng, hu_) \
          STSH(p1L + (size_t)(bb16 + 4*q + (i))*512 + ng, lu_) }
        E1(0,hc0) E1(1,hc1) E1(2,hc2) E1(3,hc3)
        #undef E1
      }
      drain_sync();
      if (tid < 96)                          // h1 group -> role2 32..95 + role3 96..127
        FADDI(mbox + (gb + 32 + tid)*32 + 4 + 4*bh + grp);
    }
  } else {
    const ushort* rH = hp + 131072;          // h1 hi plane ONLY (critical)
    const int bblk  = v & 1;
    const int kb    = (v >> 1)*256;
    const int aoff8 = (bbase + 16*bblk + col)*512 + kb + q*8;
    const int b0wL  = 16*bblk + 4*q;
    for (int t = 0; t < TT; ++t){
      waitq2(myline + 4, myline + 8, 8*(t+1), tid);   // h1[t] both halves
      f32x4 acc0={0,0,0,0};
      {
        DECL_HI8(rH)
        RUN8(MS1H)
      }
      if (v >= 2)
        *(f32x4*)&S3.xk[bblk][l][0] = acc0;
      __syncthreads();
      if (v < 2){
        acc0 += *(const f32x4*)&S3.xk[bblk][l][0];
        float s0 = S3.wo2v[col]*fmaxf(acc0[0] + S3.bo1v[col], 0.f);
        float s1 = S3.wo2v[col]*fmaxf(acc0[1] + S3.bo1v[col], 0.f);
        float s2 = S3.wo2v[col]*fmaxf(acc0[2] + S3.bo1v[col], 0.f);
        float s3 = S3.wo2v[col]*fmaxf(acc0[3] + S3.bo1v[col], 0.f);
        #pragma unroll
        for (int d = 1; d < 16; d <<= 1){
          s0 += __shfl_xor(s0, d);
          s1 += __shfl_xor(s1, d);
          s2 += __shfl_xor(s2, d);
          s3 += __shfl_xor(s3, d);
        }
        if (col == 0){
          float* rp = yout + (t&1)*2048 + j*64 + bbase + b0wL;
          f32x4 sv = {s0, s1, s2, s3};
          ST4SC(rp, sv)
        }
      }
      drain_sync();
      if (tid < 32)                          // y group -> role0 lines
        FADDI(mbox + (gb + tid)*32 + 12 + grp);
    }
  }

  // ---------------- finale: one global release/acquire barrier ------------
  gbar(gslots, epoch, wg, tid, 2);
  if (wg == 0 && tid < 64){
    float s = 0.f;
    const float* yp = yout + 2048 + tid;     // parity of t=1023 is 1
    #pragma unroll
    for (int jj = 0; jj < 32; ++jj) s += ALDF(yp + jj*64);
    out[(size_t)tid*TT + 1023] = fmaxf(s + bo2v, 0.f);
  }
  {
    int g = wg*256 + tid;                    // 256 WGs x 256 thr = 65536
    if (g < 32768) out[65536 + g] = bf2f(hp[g]) + bf2f(hp[65536 + g]);
    else {
      int g2 = g - 32768;
      out[65536 + g] = bf2f(hp[131072 + g2]) + bf2f(hp[163840 + g2]);
    }
  }
}

extern "C" void kernel_launch(void* const* d_in, const int* in_sizes, int n_in,
                              void* d_out, int out_size, void* d_ws, size_t ws_size,
                              hipStream_t stream){
  const float* ctx   = (const float*)d_in[0];
  const float* Wih0  = (const float*)d_in[2];
  const float* Whh0  = (const float*)d_in[3];
  const float* bih0  = (const float*)d_in[4];
  const float* bhh0  = (const float*)d_in[5];
  const float* Wih1  = (const float*)d_in[6];
  const float* Whh1  = (const float*)d_in[7];
  const float* bih1  = (const float*)d_in[8];
  const float* bhh1  = (const float*)d_in[9];
  const float* Wo1   = (const float*)d_in[10];
  const float* bo1   = (const float*)d_in[11];
  const float* Wo2   = (const float*)d_in[12];
  const float* bo2   = (const float*)d_in[13];

  (void)in_sizes; (void)n_in; (void)out_size; (void)ws_size;

  const int smem_sz = (int)sizeof(SmemR2);   // largest overlay (162,304 B)
  (void)hipFuncSetAttribute((const void*)decoder_rnn,
                            hipFuncAttributeMaxDynamicSharedMemorySize,
                            smem_sz);

  decoder_rnn<<<NWG, NT, smem_sz, stream>>>(
      ctx, Wih0, Whh0, bih0, bhh0, Wih1, Whh1, bih1, bhh1,
      Wo1, bo1, Wo2, bo2, (float*)d_out, (float*)d_ws);
}

// Round 12
// 8451.114 us; speedup vs baseline: 1.2485x; 1.0624x over previous
//
#include <hip/hip_runtime.h>
#include <stdint.h>

// DecoderRNN R27: R26 resubmit with the FOLDV macro fixed (parameter was
// named `x`, so member access `.x` was macro-substituted -> `ha0.ha0`;
// renamed to `V`). Design unchanged from R26:
//  R23 base (8.77ms proven) + epoch-TAGGED planes -> producer drains REMOVED
//  from all three hops. bit0 of every stored ushort (hi AND lo planes)
//  carries step parity; lo = residual of TAGGED hi so hi+lo stays exact for
//  full-precision consumers; hi-only consumers see <=1ulp (vs 0.5ulp).
//  y partials tag fp32 bit0 (2^-24). Producers: stores -> __syncthreads ->
//  FADDI (no vmcnt(0)). Consumers: R23's cheap poll, then PER-WAVE tag
//  validation on the loaded data (__all fold, retry+sleep; rare).
//  ABA excluded: adjacent generations of every buffer have distinct tags;
//  producer's next-step load-vmcnt(0) bounds staleness to 1 gen.
//  Tag parities: h0 written@t: ((t>>1)&1)^1; h1 written@t: (t&1)^1;
//  yout written@t: ((t>>1)&1)^1. Zero-init (bit0=0) differs from first tag.
//  One drain_sync before gbar(2) restores finale guarantees.

#define NWG 256
#define NT  256
#define TT  1024

typedef unsigned short ushort;
typedef unsigned int   uint;
typedef __attribute__((ext_vector_type(8))) short short8;
typedef __attribute__((ext_vector_type(4))) float f32x4;
typedef __attribute__((ext_vector_type(4))) uint  uint4v;

struct __align__(16) SmemR0 {
  ushort wpl[2][48*520];     // Whh0 hi/lo
  float  gictx[3*16*68];
  float  wcol[3][16];
  float  bhnN[16];
  float  prevS[64];          // [0..32) used
};
struct __align__(16) SmemR2 {
  ushort whh[2][48*520];     // Whh1 hi/lo (full precision, self-recurrence)
  ushort wih[48*520];        // Wih1 HI ONLY (critical path)
  float  xk[3][64][16];      // k-quarter combine: {R,Z,Ni,Nh} x4
  float  bsumR[16], bsumZ[16], binN[16], bhnN[16];
};
struct __align__(16) SmemR3 {
  ushort wpl[2][16*520];     // Wo1 block hi/lo
  float  xk[2][64][4];
  float  bo1v[16], wo2v[16];
};

__device__ __forceinline__ float frcp(float x){
#if __has_builtin(__builtin_amdgcn_rcpf)
  return __builtin_amdgcn_rcpf(x);
#else
  return 1.f/x;
#endif
}
__device__ __forceinline__ float sigm(float x){ return frcp(1.f + __expf(-x)); }
__device__ __forceinline__ float tanh_f(float x){
  return 1.f - 2.f*frcp(__expf(2.f*x) + 1.f);
}
__device__ __forceinline__ float bf2f(ushort h){ return __uint_as_float(((uint)h)<<16); }
__device__ __forceinline__ ushort bfrnd(float x){
  uint u = __float_as_uint(x);
  return (ushort)((u + 0x7fffu + ((u>>16)&1u)) >> 16);
}
#define SWP(p, v)  (void)__hip_atomic_exchange((uint*)(p), (uint)(v), __ATOMIC_RELAXED, __HIP_MEMORY_SCOPE_AGENT)
#define ALD1(p)    __hip_atomic_load((const uint*)(p), __ATOMIC_RELAXED, __HIP_MEMORY_SCOPE_AGENT)
#define ALDF(p)    __uint_as_float(ALD1(p))
#define FADDI(p)   (void)__hip_atomic_fetch_add((p), 1, __ATOMIC_RELAXED, __HIP_MEMORY_SCOPE_AGENT)

__device__ __forceinline__ void gbar(int* slots, int* epoch, int w, int tid, int e){
  __syncthreads();
  if (tid == 0)
    __hip_atomic_store(&slots[w], e, __ATOMIC_RELEASE, __HIP_MEMORY_SCOPE_AGENT);
  if (w == 0 && tid < 64){
    for(;;){
      int m0 = __hip_atomic_load(&slots[tid*4+0], __ATOMIC_RELAXED, __HIP_MEMORY_SCOPE_AGENT);
      int m1 = __hip_atomic_load(&slots[tid*4+1], __ATOMIC_RELAXED, __HIP_MEMORY_SCOPE_AGENT);
      int m2 = __hip_atomic_load(&slots[tid*4+2], __ATOMIC_RELAXED, __HIP_MEMORY_SCOPE_AGENT);
      int m3 = __hip_atomic_load(&slots[tid*4+3], __ATOMIC_RELAXED, __HIP_MEMORY_SCOPE_AGENT);
      if (__all(min(min(m0,m1),min(m2,m3)) >= e)) break;
      __builtin_amdgcn_s_sleep(1);
    }
    if (tid == 0){
      __builtin_amdgcn_fence(__ATOMIC_ACQUIRE, "agent");
      __hip_atomic_store(epoch, e, __ATOMIC_RELEASE, __HIP_MEMORY_SCOPE_AGENT);
    }
  }
  if (tid == 0){
    while (__hip_atomic_load(epoch, __ATOMIC_RELAXED, __HIP_MEMORY_SCOPE_AGENT) < e)
      __builtin_amdgcn_s_sleep(1);
    __builtin_amdgcn_fence(__ATOMIC_ACQUIRE, "agent");
  }
  __syncthreads();
}

__device__ __forceinline__ void drain_sync(){
  __builtin_amdgcn_s_waitcnt(0);
  __syncthreads();
}
// consumer poll: 1 lane, 1 dword (R23-proven shape; flag is now a HINT,
// freshness proven by tags on the data itself)
__device__ __forceinline__ void waitmail(const int* w, int target, int tid){
  if (tid == 0)
    while ((int)ALD1(w) < target) {}
  __syncthreads();
}
__device__ __forceinline__ void waitmail2(const int* a, const int* b, int target, int tid){
  if (tid == 0)
    while ((int)ALD1(a) < target || (int)ALD1(b) < target) {}
  __syncthreads();
}

// coherent LLC-direct ops (sc0 sc1 = bypass L1+L2, coalesced)
#define LD1SCD(dst, addr) \
  asm volatile("global_load_dword %0, %1, off sc0 sc1" : "=v"(dst) : "v"(addr));
#define STSH(addr, val) \
  asm volatile("global_store_short %0, %1, off sc0 sc1" :: "v"(addr), "v"(val) : "memory");
#define ST4SC(addr, val) \
  asm volatile("global_store_dwordx4 %0, %1, off sc0 sc1" :: "v"(addr), "v"(val) : "memory");
#define LD4A(DST, P, OFS) \
  asm volatile("global_load_dwordx4 %0, %1, off sc0 sc1" : "=v"(DST) : "v"((P) + (OFS)));
#define VMBAR4(a,b,c,d) \
  asm volatile("s_waitcnt vmcnt(0)" : "+v"(a),"+v"(b),"+v"(c),"+v"(d));
#define VMBAR8(a,b,c,d,e,f,g,h) \
  asm volatile("s_waitcnt vmcnt(0)" \
               : "+v"(a),"+v"(b),"+v"(c),"+v"(d),"+v"(e),"+v"(f),"+v"(g),"+v"(h));

// ---- tag machinery --------------------------------------------------------
#define TAGM 0x00010001u
// fold tag-bit mismatches of one uint4v (2 tagged ushorts per dword)
#define FOLDV(V) fo_ |= ((V.x^em_)&TAGM)|((V.y^em_)&TAGM)| \
                        ((V.z^em_)&TAGM)|((V.w^em_)&TAGM);
#define FOLD4(p)  FOLDV(p##0) FOLDV(p##1) FOLDV(p##2) FOLDV(p##3)
#define FOLD8(p)  FOLD4(p) FOLDV(p##4) FOLDV(p##5) FOLDV(p##6) FOLDV(p##7)
#define FOLD16(p) FOLD8(p) FOLDV(p##8) FOLDV(p##9) FOLDV(p##10) FOLDV(p##11) \
                  FOLDV(p##12) FOLDV(p##13) FOLDV(p##14) FOLDV(p##15)

#define MFMA_ __builtin_amdgcn_mfma_f32_16x16x32_bf16

// ---------------- role0: full-K hi/lo (waves 0,1) ----------------
#define DECL_HILO(PH, PL) \
  uint4v ha0,ha1,ha2,ha3,ha4,ha5,ha6,ha7,ha8,ha9,ha10,ha11,ha12,ha13,ha14,ha15; \
  uint4v la0,la1,la2,la3,la4,la5,la6,la7,la8,la9,la10,la11,la12,la13,la14,la15; \
  LD4A(ha0,PH,aoffB+0*32) LD4A(ha1,PH,aoffB+1*32) LD4A(ha2,PH,aoffB+2*32) LD4A(ha3,PH,aoffB+3*32) \
  LD4A(ha4,PH,aoffB+4*32) LD4A(ha5,PH,aoffB+5*32) LD4A(ha6,PH,aoffB+6*32) LD4A(ha7,PH,aoffB+7*32) \
  LD4A(ha8,PH,aoffB+8*32) LD4A(ha9,PH,aoffB+9*32) LD4A(ha10,PH,aoffB+10*32) LD4A(ha11,PH,aoffB+11*32) \
  LD4A(ha12,PH,aoffB+12*32) LD4A(ha13,PH,aoffB+13*32) LD4A(ha14,PH,aoffB+14*32) LD4A(ha15,PH,aoffB+15*32) \
  LD4A(la0,PL,aoffB+0*32) LD4A(la1,PL,aoffB+1*32) LD4A(la2,PL,aoffB+2*32) LD4A(la3,PL,aoffB+3*32) \
  LD4A(la4,PL,aoffB+4*32) LD4A(la5,PL,aoffB+5*32) LD4A(la6,PL,aoffB+6*32) LD4A(la7,PL,aoffB+7*32) \
  LD4A(la8,PL,aoffB+8*32) LD4A(la9,PL,aoffB+9*32) LD4A(la10,PL,aoffB+10*32) LD4A(la11,PL,aoffB+11*32) \
  LD4A(la12,PL,aoffB+12*32) LD4A(la13,PL,aoffB+13*32) LD4A(la14,PL,aoffB+14*32) LD4A(la15,PL,aoffB+15*32) \
  VMBAR8(ha0,ha1,ha2,ha3,ha4,ha5,ha6,ha7) \
  VMBAR8(ha8,ha9,ha10,ha11,ha12,ha13,ha14,ha15) \
  VMBAR8(la0,la1,la2,la3,la4,la5,la6,la7) \
  VMBAR8(la8,la9,la10,la11,la12,la13,la14,la15)

#define MS3F(i) { \
  short8 AH_ = __builtin_bit_cast(short8, ha##i); \
  short8 AL_ = __builtin_bit_cast(short8, la##i); \
  const int ko_ = (i)*32 + q*8; \
  short8 bh_ = *(const short8*)(&S0.wpl[0][(col)*520 + ko_]); \
  short8 bl_ = *(const short8*)(&S0.wpl[1][(col)*520 + ko_]); \
  acc0 = MFMA_(AH_, bh_, acc0, 0,0,0); \
  acc0 = MFMA_(AL_, bh_, acc0, 0,0,0); \
  acc0 = MFMA_(AH_, bl_, acc0, 0,0,0); \
  bh_ = *(const short8*)(&S0.wpl[0][(16+col)*520 + ko_]); \
  bl_ = *(const short8*)(&S0.wpl[1][(16+col)*520 + ko_]); \
  acc1 = MFMA_(AH_, bh_, acc1, 0,0,0); \
  acc1 = MFMA_(AL_, bh_, acc1, 0,0,0); \
  acc1 = MFMA_(AH_, bl_, acc1, 0,0,0); \
  bh_ = *(const short8*)(&S0.wpl[0][(32+col)*520 + ko_]); \
  bl_ = *(const short8*)(&S0.wpl[1][(32+col)*520 + ko_]); \
  acc2 = MFMA_(AH_, bh_, acc2, 0,0,0); \
  acc2 = MFMA_(AL_, bh_, acc2, 0,0,0); \
  acc2 = MFMA_(AH_, bl_, acc2, 0,0,0); }

// ---------------- role2: gh1 full (hi/lo A,B) + gi (hi A, hi B) ----------
#define GH1(i) { \
  short8 AH_ = __builtin_bit_cast(short8, ha##i); \
  short8 AL_ = __builtin_bit_cast(short8, la##i); \
  const int ko_ = kq + (i)*32 + q*8; \
  short8 bh_ = *(const short8*)(&S2.whh[0][(col)*520 + ko_]); \
  short8 bl_ = *(const short8*)(&S2.whh[1][(col)*520 + ko_]); \
  aR = MFMA_(AH_, bh_, aR, 0,0,0); \
  aR = MFMA_(AL_, bh_, aR, 0,0,0); \
  aR = MFMA_(AH_, bl_, aR, 0,0,0); \
  bh_ = *(const short8*)(&S2.whh[0][(16+col)*520 + ko_]); \
  bl_ = *(const short8*)(&S2.whh[1][(16+col)*520 + ko_]); \
  aZ = MFMA_(AH_, bh_, aZ, 0,0,0); \
  aZ = MFMA_(AL_, bh_, aZ, 0,0,0); \
  aZ = MFMA_(AH_, bl_, aZ, 0,0,0); \
  bh_ = *(const short8*)(&S2.whh[0][(32+col)*520 + ko_]); \
  bl_ = *(const short8*)(&S2.whh[1][(32+col)*520 + ko_]); \
  aNh = MFMA_(AH_, bh_, aNh, 0,0,0); \
  aNh = MFMA_(AL_, bh_, aNh, 0,0,0); \
  aNh = MFMA_(AH_, bl_, aNh, 0,0,0); }

#define GI1(i) { \
  short8 AH_ = __builtin_bit_cast(short8, ga##i); \
  const int ko_ = kq + (i)*32 + q*8; \
  short8 bh_ = *(const short8*)(&S2.wih[(col)*520 + ko_]); \
  aR = MFMA_(AH_, bh_, aR, 0,0,0); \
  bh_ = *(const short8*)(&S2.wih[(16+col)*520 + ko_]); \
  aZ = MFMA_(AH_, bh_, aZ, 0,0,0); \
  bh_ = *(const short8*)(&S2.wih[(32+col)*520 + ko_]); \
  aNi = MFMA_(AH_, bh_, aNi, 0,0,0); }

// ---------------- role3: k-half hi A, hi/lo B -----------------------------
#define DECL_HI8(P) \
  uint4v ha0,ha1,ha2,ha3,ha4,ha5,ha6,ha7; \
  LD4A(ha0,P,aoff8+0*32) LD4A(ha1,P,aoff8+1*32) LD4A(ha2,P,aoff8+2*32) LD4A(ha3,P,aoff8+3*32) \
  LD4A(ha4,P,aoff8+4*32) LD4A(ha5,P,aoff8+5*32) LD4A(ha6,P,aoff8+6*32) LD4A(ha7,P,aoff8+7*32) \
  VMBAR8(ha0,ha1,ha2,ha3,ha4,ha5,ha6,ha7)

#define MS1H(i) { \
  short8 AH_ = __builtin_bit_cast(short8, ha##i); \
  const int ko_ = kb + (i)*32 + q*8; \
  short8 bh_ = *(const short8*)(&S3.wpl[0][(col)*520 + ko_]); \
  short8 bl_ = *(const short8*)(&S3.wpl[1][(col)*520 + ko_]); \
  acc0 = MFMA_(AH_, bh_, acc0, 0,0,0); \
  acc0 = MFMA_(AH_, bl_, acc0, 0,0,0); }

#define RUN16(M) M(0) M(1) M(2) M(3) M(4) M(5) M(6) M(7) \
                 M(8) M(9) M(10) M(11) M(12) M(13) M(14) M(15)
#define RUN8(M)  M(0) M(1) M(2) M(3) M(4) M(5) M(6) M(7)
#define RUN4(M)  M(0) M(1) M(2) M(3)

extern "C" __global__ void __launch_bounds__(NT, 1)
decoder_rnn(const float* __restrict__ ctx,   // [64][512]
            const float* __restrict__ Wih0,  // [1536][513] (row stride 513!)
            const float* __restrict__ Whh0,
            const float* __restrict__ bih0,
            const float* __restrict__ bhh0g,
            const float* __restrict__ Wih1,
            const float* __restrict__ Whh1,
            const float* __restrict__ bih1g,
            const float* __restrict__ bhh1g,
            const float* __restrict__ Wo1,
            const float* __restrict__ bo1g,
            const float* __restrict__ Wo2,
            const float* __restrict__ bo2g,
            float* __restrict__ out,         // [64*1024 y][65536 h_i]
            float* __restrict__ ws)
{
  extern __shared__ char smem_raw[];
  SmemR0& S0 = *reinterpret_cast<SmemR0*>(smem_raw);
  SmemR2& S2 = *reinterpret_cast<SmemR2*>(smem_raw);
  SmemR3& S3 = *reinterpret_cast<SmemR3*>(smem_raw);
  const int tid = threadIdx.x;
  const int wg  = blockIdx.x;

  ushort* hp  = (ushort*)ws;                 // h0hi[2]@0/32768, h0lo[2]@65536/
                                             // 98304, h1hi@131072, h1lo@163840
  float* yout = (float*)ws + 196608;         // 2 x 2048
  int*  ibase = (int*)((float*)ws + 200704);
  int* gslots = ibase;                       // [256] gbar
  int* epoch  = ibase + 256;
  int* mbox   = ibase + 512;                 // 256 lines x 32 ints
                                             // slots: [0]=h0, [1]=h1a/y, [2]=h1b

  const float bo2v = bo2g[0];

  // ---------------- init (swaps -> LLC; once, off critical path) ----------
  for (int i = wg*NT + tid; i < 200704; i += NWG*NT)
    SWP((uint*)ws + i, 0u);
  if (wg == 0)
    for (int i = tid; i < 256*32; i += NT) SWP(mbox + i, 0);

  const int gid   = wg >> 7;                 // 2 independent 32-batch machines
  const int m     = wg & 127;
  const int bbase = 32*gid;
  int role, j, bh = 0;
  if (m < 32){ role = 0; j = m; }
  else if (m < 96){ role = 2; bh = (m - 32) >> 5; j = m & 31; }
  else { role = 3; j = m - 96; }

  if (role == 0){
    for (int i = tid; i < 48*512; i += NT){
      int r = i >> 9, k = i & 511;
      int g3 = r >> 4, n = r & 15;
      float wv = Whh0[(size_t)(g3*512 + 16*j + n)*512 + k];
      ushort hh = bfrnd(wv);
      S0.wpl[0][r*520 + k] = hh;
      S0.wpl[1][r*520 + k] = bfrnd(wv - bf2f(hh));
    }
    if (tid < 48){
      int g3 = tid >> 4, n = tid & 15;
      S0.wcol[g3][n] = Wih0[(size_t)(g3*512 + 16*j + n)*513 + 512];
    }
    if (tid < 16) S0.bhnN[tid] = bhh0g[2*512 + 16*j + tid];
    for (int idx = tid; idx < 1536; idx += NT){   // 48 rows x 32 local b
      int r = idx >> 5, bl = idx & 31;
      int g3 = r >> 4, n = r & 15;
      int grow = g3*512 + 16*j + n;
      const float* wr = Wih0 + (size_t)grow*513;
      const float* cx = ctx  + (size_t)(bbase + bl)*512;
      float s = bih0[grow];
      if (g3 < 2) s += bhh0g[grow];
      #pragma unroll 4
      for (int k = 0; k < 512; ++k) s += wr[k]*cx[k];
      S0.gictx[g3*1088 + n*68 + bl] = s;
    }
  } else if (role == 2){
    for (int i = tid; i < 48*512; i += NT){
      int r = i >> 9, k = i & 511;
      int g3 = r >> 4, n = r & 15;
      size_t row = (size_t)(g3*512 + 16*j + n)*512 + k;
      float wv = Whh1[row];
      ushort hh = bfrnd(wv);
      S2.whh[0][r*520 + k] = hh;
      S2.whh[1][r*520 + k] = bfrnd(wv - bf2f(hh));
      S2.wih[r*520 + k] = bfrnd(Wih1[row]);       // HI ONLY
    }
    if (tid < 16){
      int n = tid;
      S2.bsumR[n] = bih1g[16*j + n]       + bhh1g[16*j + n];
      S2.bsumZ[n] = bih1g[512 + 16*j + n] + bhh1g[512 + 16*j + n];
      S2.binN[n]  = bih1g[1024 + 16*j + n];
      S2.bhnN[n]  = bhh1g[1024 + 16*j + n];
    }
  } else {
    for (int i = tid; i < 16*512; i += NT){
      int r = i >> 9, k = i & 511;
      float wv = Wo1[(size_t)(16*j + r)*512 + k];
      ushort hh = bfrnd(wv);
      S3.wpl[0][r*520 + k] = hh;
      S3.wpl[1][r*520 + k] = bfrnd(wv - bf2f(hh));
    }
    if (tid < 16){ S3.bo1v[tid] = bo1g[16*j + tid]; S3.wo2v[tid] = Wo2[16*j + tid]; }
  }

  gbar(gslots, epoch, wg, tid, 1);

  int* myline = mbox + wg*32;
  const int gb = gid*128;

  const int v   = tid >> 6;
  const int l   = tid & 63;
  const int q   = l >> 4;
  const int col = l & 15;
  const int ng  = 16*j + col;

  if (role == 0){
    const int bblk  = v & 1;
    const int aoffB = (bbase + 16*bblk + col)*512 + q*8;
    const int b0wL  = 16*bblk + 4*q;
    float hc0 = 0.f, hc1 = 0.f, hc2 = 0.f, hc3 = 0.f;
    for (int t = 0; t < TT; ++t){
      const int r0 = t & 1, w0 = r0 ^ 1;
      waitmail(myline + 0, 32*t, tid);       // HINT: h0[t-1] issued
      const ushort* rH = hp + r0*32768;
      const ushort* rL = hp + 65536 + r0*32768;
      ushort*       wH = hp + w0*32768;
      ushort*       wL = hp + 65536 + w0*32768;
      f32x4 acc0={0,0,0,0}, acc1={0,0,0,0}, acc2={0,0,0,0};
      if (v < 2){
        const uint em_ = (t==0) ? 0u : (((((t-1)>>1)&1u)^1u) * TAGM);
        for(;;){
          DECL_HILO(rH, rL)
          uint fo_ = 0u;
          FOLD16(ha) FOLD16(la)
          if (__all((int)(fo_ == 0u))){ RUN16(MS3F) break; }
          __builtin_amdgcn_s_sleep(1);
        }
      }
      waitmail(myline + 1, 32*t, tid);       // HINT: y[t-1] issued
      if (v == 0){
        float s = 0.f;
        if (t > 0){
          const uint ey_ = (((t-1)>>1)&1u)^1u;
          const float* yp = yout + ((t-1)&1)*2048 + bbase + l;
          for(;;){
            float vv[32]; uint fo_ = 0u;
            if (l < 32){
              #pragma unroll
              for (int jj = 0; jj < 32; ++jj)
                LD1SCD(vv[jj], yp + jj*64)
              VMBAR8(vv[0],vv[1],vv[2],vv[3],vv[4],vv[5],vv[6],vv[7])
              VMBAR8(vv[8],vv[9],vv[10],vv[11],vv[12],vv[13],vv[14],vv[15])
              VMBAR8(vv[16],vv[17],vv[18],vv[19],vv[20],vv[21],vv[22],vv[23])
              VMBAR8(vv[24],vv[25],vv[26],vv[27],vv[28],vv[29],vv[30],vv[31])
              #pragma unroll
              for (int jj = 0; jj < 32; ++jj)
                fo_ |= (__float_as_uint(vv[jj]) ^ ey_) & 1u;
            }
            if (__all((int)(fo_ == 0u))){
              if (l < 32){
                #pragma unroll
                for (int st = 16; st >= 1; st >>= 1)
                  #pragma unroll
                  for (int k2 = 0; k2 < st; ++k2) vv[k2] += vv[k2 + st];
                s = vv[0];
              }
              break;
            }
            __builtin_amdgcn_s_sleep(1);
          }
        }
        if (l < 32){
          float pv = fmaxf(s + bo2v, 0.f);
          S0.prevS[l] = pv;
          if (j == 0 && t > 0) out[(size_t)(bbase + l)*TT + (t-1)] = pv;
        }
      }
      __syncthreads();
      if (v < 2){
        const uint tg0_ = ((t>>1)&1u)^1u;
        f32x4 pv4 = *(const f32x4*)&S0.prevS[b0wL];
        f32x4 gR = *(const f32x4*)&S0.gictx[0*1088 + col*68 + b0wL];
        f32x4 gZ = *(const f32x4*)&S0.gictx[1*1088 + col*68 + b0wL];
        f32x4 gN = *(const f32x4*)&S0.gictx[2*1088 + col*68 + b0wL];
        float wc0 = S0.wcol[0][col], wc1 = S0.wcol[1][col], wc2 = S0.wcol[2][col];
        float bhn = S0.bhnN[col];
        #define E0(i, HC) { \
          float rr = sigm(gR[i] + pv4[i]*wc0 + acc0[i]); \
          float zz = sigm(gZ[i] + pv4[i]*wc1 + acc1[i]); \
          float nn = tanh_f(gN[i] + pv4[i]*wc2 + rr*(acc2[i] + bhn)); \
          float h = (1.f-zz)*nn + zz*HC; \
          HC = h; \
          uint hu_ = ((uint)bfrnd(h) & 0xFFFEu) | tg0_; \
          uint lu_ = ((uint)bfrnd(h - bf2f((ushort)hu_)) & 0xFFFEu) | tg0_; \
          STSH(wH + (size_t)(bbase + b0wL + (i))*512 + ng, hu_) \
          STSH(wL + (size_t)(bbase + b0wL + (i))*512 + ng, lu_) }
        E0(0,hc0) E0(1,hc1) E0(2,hc2) E0(3,hc3)
        #undef E0
      }
      __syncthreads();                       // all stores ISSUED (no drain)
      if (tid < 96)                          // h0 flag -> role0 + role2 lines
        FADDI(mbox + (gb + tid)*32 + 0);
    }
  } else if (role == 2){
    ushort* p1H = hp + 131072;
    ushort* p1L = hp + 163840;
    const int bb16  = bbase + 16*bh;
    const int kq    = v*128;                 // k-quarter per wave
    const int aoffA = (bb16 + col)*512 + kq + q*8;
    float hc0 = 0.f, hc1 = 0.f, hc2 = 0.f, hc3 = 0.f;   // wave0: batches 4q+i
    for (int t = 0; t < TT; ++t){
      // -------- phase A (slack-funded): gh1 = Whh1 @ h1[t-1], full prec ----
      waitmail(myline + 1 + bh, 32*t, tid);  // HINT: own-half h1[t-1] issued
      f32x4 aR={0,0,0,0}, aZ={0,0,0,0}, aNi={0,0,0,0}, aNh={0,0,0,0};
      {
        const uint em_ = (t==0) ? 0u : ((((t-1)&1u)^1u) * TAGM);
        for(;;){
          uint4v ha0,ha1,ha2,ha3, la0,la1,la2,la3;
          LD4A(ha0, p1H, aoffA+0*32) LD4A(ha1, p1H, aoffA+1*32)
          LD4A(ha2, p1H, aoffA+2*32) LD4A(ha3, p1H, aoffA+3*32)
          LD4A(la0, p1L, aoffA+0*32) LD4A(la1, p1L, aoffA+1*32)
          LD4A(la2, p1L, aoffA+2*32) LD4A(la3, p1L, aoffA+3*32)
          VMBAR8(ha0,ha1,ha2,ha3,la0,la1,la2,la3)
          uint fo_ = 0u;
          FOLD4(ha) FOLD4(la)
          if (__all((int)(fo_ == 0u))){ RUN4(GH1) break; }
          __builtin_amdgcn_s_sleep(1);
        }
      }
      // -------- phase B (critical): gi = Wih1_hi @ h0hi[t] ----------------
      waitmail(myline + 0, 32*(t+1), tid);   // HINT: h0[t] issued
      {
        const uint em_ = (((t>>1)&1u)^1u) * TAGM;
        const ushort* rH = hp + ((t & 1) ^ 1)*32768;
        for(;;){
          uint4v ga0,ga1,ga2,ga3;
          LD4A(ga0, rH, aoffA+0*32) LD4A(ga1, rH, aoffA+1*32)
          LD4A(ga2, rH, aoffA+2*32) LD4A(ga3, rH, aoffA+3*32)
          VMBAR4(ga0,ga1,ga2,ga3)
          uint fo_ = 0u;
          FOLD4(ga)
          if (__all((int)(fo_ == 0u))){ RUN4(GI1) break; }
          __builtin_amdgcn_s_sleep(1);
        }
      }
      // -------- combine k-quarters, EW, store -----------------------------
      if (v >= 1){
        *(f32x4*)&S2.xk[v-1][l][0]  = aR;
        *(f32x4*)&S2.xk[v-1][l][4]  = aZ;
        *(f32x4*)&S2.xk[v-1][l][8]  = aNi;
        *(f32x4*)&S2.xk[v-1][l][12] = aNh;
      }
      __syncthreads();
      if (v == 0){
        const uint tg1_ = (t&1u)^1u;
        #pragma unroll
        for (int w = 0; w < 3; ++w){
          aR  += *(const f32x4*)&S2.xk[w][l][0];
          aZ  += *(const f32x4*)&S2.xk[w][l][4];
          aNi += *(const f32x4*)&S2.xk[w][l][8];
          aNh += *(const f32x4*)&S2.xk[w][l][12];
        }
        float bsR = S2.bsumR[col], bsZ = S2.bsumZ[col];
        float biN = S2.binN[col],  bhN = S2.bhnN[col];
        #define E1(i, HC) { \
          float r1 = sigm(aR[i] + bsR); \
          float z1 = sigm(aZ[i] + bsZ); \
          float n1 = tanh_f(aNi[i] + biN + r1*(aNh[i] + bhN)); \
          float h = (1.f-z1)*n1 + z1*HC; \
          HC = h; \
          uint hu_ = ((uint)bfrnd(h) & 0xFFFEu) | tg1_; \
          uint lu_ = ((uint)bfrnd(h - bf2f((ushort)hu_)) & 0xFFFEu) | tg1_; \
          STSH(p1H + (size_t)(bb16 + 4*q + (i))*512 + ng, hu_) \
          STSH(p1L + (size_t)(bb16 + 4*q + (i))*512 + ng, lu_) }
        E1(0,hc0) E1(1,hc1) E1(2,hc2) E1(3,hc3)
        #undef E1
      }
      __syncthreads();                       // all stores ISSUED (no drain)
      if (tid < 96)                          // h1 flag -> role2 + role3 lines
        FADDI(mbox + (gb + 32 + tid)*32 + 1 + bh);
    }
  } else {
    const ushort* rH = hp + 131072;          // h1 hi plane ONLY (critical)
    const int bblk  = v & 1;
    const int kb    = (v >> 1)*256;
    const int aoff8 = (bbase + 16*bblk + col)*512 + kb + q*8;
    const int b0wL  = 16*bblk + 4*q;
    for (int t = 0; t < TT; ++t){
      waitmail2(myline + 1, myline + 2, 32*(t+1), tid);  // HINT: h1[t] issued
      f32x4 acc0={0,0,0,0};
      {
        const uint em_ = ((t&1u)^1u) * TAGM;
        for(;;){
          DECL_HI8(rH)
          uint fo_ = 0u;
          FOLD8(ha)
          if (__all((int)(fo_ == 0u))){ RUN8(MS1H) break; }
          __builtin_amdgcn_s_sleep(1);
        }
      }
      if (v >= 2)
        *(f32x4*)&S3.xk[bblk][l][0] = acc0;
      __syncthreads();
      if (v < 2){
        acc0 += *(const f32x4*)&S3.xk[bblk][l][0];
        float s0 = S3.wo2v[col]*fmaxf(acc0[0] + S3.bo1v[col], 0.f);
        float s1 = S3.wo2v[col]*fmaxf(acc0[1] + S3.bo1v[col], 0.f);
        float s2 = S3.wo2v[col]*fmaxf(acc0[2] + S3.bo1v[col], 0.f);
        float s3 = S3.wo2v[col]*fmaxf(acc0[3] + S3.bo1v[col], 0.f);
        #pragma unroll
        for (int d = 1; d < 16; d <<= 1){
          s0 += __shfl_xor(s0, d);
          s1 += __shfl_xor(s1, d);
          s2 += __shfl_xor(s2, d);
          s3 += __shfl_xor(s3, d);
        }
        if (col == 0){
          const uint tgy_ = ((t>>1)&1u)^1u;
          uint* rp = (uint*)(yout + (t&1)*2048 + j*64 + bbase + b0wL);
          uint4v uv = { (__float_as_uint(s0) & ~1u) | tgy_,
                        (__float_as_uint(s1) & ~1u) | tgy_,
                        (__float_as_uint(s2) & ~1u) | tgy_,
                        (__float_as_uint(s3) & ~1u) | tgy_ };
          ST4SC(rp, uv)
        }
      }
      __syncthreads();                       // all stores ISSUED (no drain)
      if (tid < 32)                          // y flag -> role0 lines
        FADDI(mbox + (gb + tid)*32 + 1);
    }
  }

  // ---------------- finale: drain once, then global barrier ---------------
  drain_sync();
  gbar(gslots, epoch, wg, tid, 2);
  if (wg == 0 && tid < 64){
    float s = 0.f;
    const float* yp = yout + 2048 + tid;     // parity of t=1023 is 1
    #pragma unroll
    for (int jj = 0; jj < 32; ++jj) s += ALDF(yp + jj*64);
    out[(size_t)tid*TT + 1023] = fmaxf(s + bo2v, 0.f);
  }
  {
    int g = wg*256 + tid;                    // 256 WGs x 256 thr = 65536
    if (g < 32768) out[65536 + g] = bf2f(hp[g]) + bf2f(hp[65536 + g]);
    else {
      int g2 = g - 32768;
      out[65536 + g] = bf2f(hp[131072 + g2]) + bf2f(hp[163840 + g2]);
    }
  }
}

extern "C" void kernel_launch(void* const* d_in, const int* in_sizes, int n_in,
                              void* d_out, int out_size, void* d_ws, size_t ws_size,
                              hipStream_t stream){
  const float* ctx   = (const float*)d_in[0];
  const float* Wih0  = (const float*)d_in[2];
  const float* Whh0  = (const float*)d_in[3];
  const float* bih0  = (const float*)d_in[4];
  const float* bhh0  = (const float*)d_in[5];
  const float* Wih1  = (const float*)d_in[6];
  const float* Whh1  = (const float*)d_in[7];
  const float* bih1  = (const float*)d_in[8];
  const float* bhh1  = (const float*)d_in[9];
  const float* Wo1   = (const float*)d_in[10];
  const float* bo1   = (const float*)d_in[11];
  const float* Wo2   = (const float*)d_in[12];
  const float* bo2   = (const float*)d_in[13];

  (void)in_sizes; (void)n_in; (void)out_size; (void)ws_size;

  const int smem_sz = (int)sizeof(SmemR2);   // largest overlay (162,304 B)
  (void)hipFuncSetAttribute((const void*)decoder_rnn,
                            hipFuncAttributeMaxDynamicSharedMemorySize,
                            smem_sz);

  decoder_rnn<<<NWG, NT, smem_sz, stream>>>(
      ctx, Wih0, Whh0, bih0, bhh0, Wih1, Whh1, bih1, bhh1,
      Wo1, bo1, Wo2, bo2, (float*)d_out, (float*)d_ws);
}

// Round 13
// 8297.014 us; speedup vs baseline: 1.2717x; 1.0186x over previous
//
#include <hip/hip_runtime.h>
#include <stdint.h>

// DecoderRNN R28: R27 base (8.45ms) + CANARY polling -> flag system deleted.
//  R27's tags make data self-describing; the FADDI flag + poll indirection
//  is redundant. Consumers now poll a 16B CANARY inside their own data slice
//  (tid0, ONE LLC request per iteration -- identical poll cost to the proven
//  R23/R27 shape; avoids the R21/R24 poll-traffic regressions), then do the
//  full load with the existing per-wave tag validation (stragglers -> rare
//  retry+sleep). Removes per hop: producer FADDI visibility (~1 RTT) and
//  flag->data indirection. mbox gone from the loop; gbar kept init/finale.
//  Canary sites (expected tag = the em used by that phase's validation):
//   role0 h0:  rH + bbase*512            (h0 written@t tag ((t>>1)&1)^1)
//   role0 y:   yout[par] + bbase         (fp32 bit0; y@t tag ((t>>1)&1)^1)
//   role2 A:   p1H + bb16*512            (h1 written@t tag (t&1)^1)
//   role2 B:   rH + bb16*512             (h0 tag)
//   role3:     h1hi + {bbase, bbase+16}*512  (both batch halves)
//  All distinct from zero-init (0) and from the buffer's previous occupant.
// Everything else byte-identical to R27 (role1 eliminated, role2 x64 4-way
// K-split w/ slack-funded gh1, Wih1 hi-only, tagged planar hi/lo h).

#define NWG 256
#define NT  256
#define TT  1024

typedef unsigned short ushort;
typedef unsigned int   uint;
typedef __attribute__((ext_vector_type(8))) short short8;
typedef __attribute__((ext_vector_type(4))) float f32x4;
typedef __attribute__((ext_vector_type(4))) uint  uint4v;

struct __align__(16) SmemR0 {
  ushort wpl[2][48*520];     // Whh0 hi/lo
  float  gictx[3*16*68];
  float  wcol[3][16];
  float  bhnN[16];
  float  prevS[64];          // [0..32) used
};
struct __align__(16) SmemR2 {
  ushort whh[2][48*520];     // Whh1 hi/lo (full precision, self-recurrence)
  ushort wih[48*520];        // Wih1 HI ONLY (critical path)
  float  xk[3][64][16];      // k-quarter combine: {R,Z,Ni,Nh} x4
  float  bsumR[16], bsumZ[16], binN[16], bhnN[16];
};
struct __align__(16) SmemR3 {
  ushort wpl[2][16*520];     // Wo1 block hi/lo
  float  xk[2][64][4];
  float  bo1v[16], wo2v[16];
};

__device__ __forceinline__ float frcp(float x){
#if __has_builtin(__builtin_amdgcn_rcpf)
  return __builtin_amdgcn_rcpf(x);
#else
  return 1.f/x;
#endif
}
__device__ __forceinline__ float sigm(float x){ return frcp(1.f + __expf(-x)); }
__device__ __forceinline__ float tanh_f(float x){
  return 1.f - 2.f*frcp(__expf(2.f*x) + 1.f);
}
__device__ __forceinline__ float bf2f(ushort h){ return __uint_as_float(((uint)h)<<16); }
__device__ __forceinline__ ushort bfrnd(float x){
  uint u = __float_as_uint(x);
  return (ushort)((u + 0x7fffu + ((u>>16)&1u)) >> 16);
}
#define SWP(p, v)  (void)__hip_atomic_exchange((uint*)(p), (uint)(v), __ATOMIC_RELAXED, __HIP_MEMORY_SCOPE_AGENT)
#define ALD1(p)    __hip_atomic_load((const uint*)(p), __ATOMIC_RELAXED, __HIP_MEMORY_SCOPE_AGENT)
#define ALDF(p)    __uint_as_float(ALD1(p))

__device__ __forceinline__ void gbar(int* slots, int* epoch, int w, int tid, int e){
  __syncthreads();
  if (tid == 0)
    __hip_atomic_store(&slots[w], e, __ATOMIC_RELEASE, __HIP_MEMORY_SCOPE_AGENT);
  if (w == 0 && tid < 64){
    for(;;){
      int m0 = __hip_atomic_load(&slots[tid*4+0], __ATOMIC_RELAXED, __HIP_MEMORY_SCOPE_AGENT);
      int m1 = __hip_atomic_load(&slots[tid*4+1], __ATOMIC_RELAXED, __HIP_MEMORY_SCOPE_AGENT);
      int m2 = __hip_atomic_load(&slots[tid*4+2], __ATOMIC_RELAXED, __HIP_MEMORY_SCOPE_AGENT);
      int m3 = __hip_atomic_load(&slots[tid*4+3], __ATOMIC_RELAXED, __HIP_MEMORY_SCOPE_AGENT);
      if (__all(min(min(m0,m1),min(m2,m3)) >= e)) break;
      __builtin_amdgcn_s_sleep(1);
    }
    if (tid == 0){
      __builtin_amdgcn_fence(__ATOMIC_ACQUIRE, "agent");
      __hip_atomic_store(epoch, e, __ATOMIC_RELEASE, __HIP_MEMORY_SCOPE_AGENT);
    }
  }
  if (tid == 0){
    while (__hip_atomic_load(epoch, __ATOMIC_RELAXED, __HIP_MEMORY_SCOPE_AGENT) < e)
      __builtin_amdgcn_s_sleep(1);
    __builtin_amdgcn_fence(__ATOMIC_ACQUIRE, "agent");
  }
  __syncthreads();
}

__device__ __forceinline__ void drain_sync(){
  __builtin_amdgcn_s_waitcnt(0);
  __syncthreads();
}

// coherent LLC-direct ops (sc0 sc1 = bypass L1+L2, coalesced)
#define LD1SCD(dst, addr) \
  asm volatile("global_load_dword %0, %1, off sc0 sc1" : "=v"(dst) : "v"(addr));
#define STSH(addr, val) \
  asm volatile("global_store_short %0, %1, off sc0 sc1" :: "v"(addr), "v"(val) : "memory");
#define ST4SC(addr, val) \
  asm volatile("global_store_dwordx4 %0, %1, off sc0 sc1" :: "v"(addr), "v"(val) : "memory");
#define LD4A(DST, P, OFS) \
  asm volatile("global_load_dwordx4 %0, %1, off sc0 sc1" : "=v"(DST) : "v"((P) + (OFS)));
#define VMBAR1(a)   asm volatile("s_waitcnt vmcnt(0)" : "+v"(a));
#define VMBAR2(a,b) asm volatile("s_waitcnt vmcnt(0)" : "+v"(a),"+v"(b));
#define VMBAR4(a,b,c,d) \
  asm volatile("s_waitcnt vmcnt(0)" : "+v"(a),"+v"(b),"+v"(c),"+v"(d));
#define VMBAR8(a,b,c,d,e,f,g,h) \
  asm volatile("s_waitcnt vmcnt(0)" \
               : "+v"(a),"+v"(b),"+v"(c),"+v"(d),"+v"(e),"+v"(f),"+v"(g),"+v"(h));

// ---- tag machinery --------------------------------------------------------
#define TAGM 0x00010001u
#define FOLDV(V) fo_ |= ((V.x^em_)&TAGM)|((V.y^em_)&TAGM)| \
                        ((V.z^em_)&TAGM)|((V.w^em_)&TAGM);
#define FOLD4(p)  FOLDV(p##0) FOLDV(p##1) FOLDV(p##2) FOLDV(p##3)
#define FOLD8(p)  FOLD4(p) FOLDV(p##4) FOLDV(p##5) FOLDV(p##6) FOLDV(p##7)
#define FOLD16(p) FOLD8(p) FOLDV(p##8) FOLDV(p##9) FOLDV(p##10) FOLDV(p##11) \
                  FOLDV(p##12) FOLDV(p##13) FOLDV(p##14) FOLDV(p##15)

// canary poll: tid0 loads 16B of the DATA plane; fresh when all 8 tags match
__device__ __forceinline__ void waitcan(const ushort* p, uint em, int tid){
  if (tid == 0){
    for(;;){
      uint4v c;
      LD4A(c, (const uint*)p, 0)
      VMBAR1(c)
      uint fo = ((c.x^em)&TAGM)|((c.y^em)&TAGM)|((c.z^em)&TAGM)|((c.w^em)&TAGM);
      if (fo == 0u) break;
    }
  }
  __syncthreads();
}
// two canaries in one parallel batch (role3's batch halves)
__device__ __forceinline__ void waitcan2(const ushort* pa, const ushort* pb,
                                         uint em, int tid){
  if (tid == 0){
    for(;;){
      uint4v a, b;
      LD4A(a, (const uint*)pa, 0)
      LD4A(b, (const uint*)pb, 0)
      VMBAR2(a, b)
      uint fo = ((a.x^em)&TAGM)|((a.y^em)&TAGM)|((a.z^em)&TAGM)|((a.w^em)&TAGM)
              | ((b.x^em)&TAGM)|((b.y^em)&TAGM)|((b.z^em)&TAGM)|((b.w^em)&TAGM);
      if (fo == 0u) break;
    }
  }
  __syncthreads();
}
// y canary: single fp32, bit0 parity
__device__ __forceinline__ void waitcany(const float* p, uint ey, int tid){
  if (tid == 0){
    for(;;){
      uint c;
      asm volatile("global_load_dword %0, %1, off sc0 sc1" : "=v"(c) : "v"(p));
      VMBAR1(c)
      if (((c ^ ey) & 1u) == 0u) break;
    }
  }
  __syncthreads();
}

#define MFMA_ __builtin_amdgcn_mfma_f32_16x16x32_bf16

// ---------------- role0: full-K hi/lo (waves 0,1) ----------------
#define DECL_HILO(PH, PL) \
  uint4v ha0,ha1,ha2,ha3,ha4,ha5,ha6,ha7,ha8,ha9,ha10,ha11,ha12,ha13,ha14,ha15; \
  uint4v la0,la1,la2,la3,la4,la5,la6,la7,la8,la9,la10,la11,la12,la13,la14,la15; \
  LD4A(ha0,PH,aoffB+0*32) LD4A(ha1,PH,aoffB+1*32) LD4A(ha2,PH,aoffB+2*32) LD4A(ha3,PH,aoffB+3*32) \
  LD4A(ha4,PH,aoffB+4*32) LD4A(ha5,PH,aoffB+5*32) LD4A(ha6,PH,aoffB+6*32) LD4A(ha7,PH,aoffB+7*32) \
  LD4A(ha8,PH,aoffB+8*32) LD4A(ha9,PH,aoffB+9*32) LD4A(ha10,PH,aoffB+10*32) LD4A(ha11,PH,aoffB+11*32) \
  LD4A(ha12,PH,aoffB+12*32) LD4A(ha13,PH,aoffB+13*32) LD4A(ha14,PH,aoffB+14*32) LD4A(ha15,PH,aoffB+15*32) \
  LD4A(la0,PL,aoffB+0*32) LD4A(la1,PL,aoffB+1*32) LD4A(la2,PL,aoffB+2*32) LD4A(la3,PL,aoffB+3*32) \
  LD4A(la4,PL,aoffB+4*32) LD4A(la5,PL,aoffB+5*32) LD4A(la6,PL,aoffB+6*32) LD4A(la7,PL,aoffB+7*32) \
  LD4A(la8,PL,aoffB+8*32) LD4A(la9,PL,aoffB+9*32) LD4A(la10,PL,aoffB+10*32) LD4A(la11,PL,aoffB+11*32) \
  LD4A(la12,PL,aoffB+12*32) LD4A(la13,PL,aoffB+13*32) LD4A(la14,PL,aoffB+14*32) LD4A(la15,PL,aoffB+15*32) \
  VMBAR8(ha0,ha1,ha2,ha3,ha4,ha5,ha6,ha7) \
  VMBAR8(ha8,ha9,ha10,ha11,ha12,ha13,ha14,ha15) \
  VMBAR8(la0,la1,la2,la3,la4,la5,la6,la7) \
  VMBAR8(la8,la9,la10,la11,la12,la13,la14,la15)

#define MS3F(i) { \
  short8 AH_ = __builtin_bit_cast(short8, ha##i); \
  short8 AL_ = __builtin_bit_cast(short8, la##i); \
  const int ko_ = (i)*32 + q*8; \
  short8 bh_ = *(const short8*)(&S0.wpl[0][(col)*520 + ko_]); \
  short8 bl_ = *(const short8*)(&S0.wpl[1][(col)*520 + ko_]); \
  acc0 = MFMA_(AH_, bh_, acc0, 0,0,0); \
  acc0 = MFMA_(AL_, bh_, acc0, 0,0,0); \
  acc0 = MFMA_(AH_, bl_, acc0, 0,0,0); \
  bh_ = *(const short8*)(&S0.wpl[0][(16+col)*520 + ko_]); \
  bl_ = *(const short8*)(&S0.wpl[1][(16+col)*520 + ko_]); \
  acc1 = MFMA_(AH_, bh_, acc1, 0,0,0); \
  acc1 = MFMA_(AL_, bh_, acc1, 0,0,0); \
  acc1 = MFMA_(AH_, bl_, acc1, 0,0,0); \
  bh_ = *(const short8*)(&S0.wpl[0][(32+col)*520 + ko_]); \
  bl_ = *(const short8*)(&S0.wpl[1][(32+col)*520 + ko_]); \
  acc2 = MFMA_(AH_, bh_, acc2, 0,0,0); \
  acc2 = MFMA_(AL_, bh_, acc2, 0,0,0); \
  acc2 = MFMA_(AH_, bl_, acc2, 0,0,0); }

// ---------------- role2: gh1 full (hi/lo A,B) + gi (hi A, hi B) ----------
#define GH1(i) { \
  short8 AH_ = __builtin_bit_cast(short8, ha##i); \
  short8 AL_ = __builtin_bit_cast(short8, la##i); \
  const int ko_ = kq + (i)*32 + q*8; \
  short8 bh_ = *(const short8*)(&S2.whh[0][(col)*520 + ko_]); \
  short8 bl_ = *(const short8*)(&S2.whh[1][(col)*520 + ko_]); \
  aR = MFMA_(AH_, bh_, aR, 0,0,0); \
  aR = MFMA_(AL_, bh_, aR, 0,0,0); \
  aR = MFMA_(AH_, bl_, aR, 0,0,0); \
  bh_ = *(const short8*)(&S2.whh[0][(16+col)*520 + ko_]); \
  bl_ = *(const short8*)(&S2.whh[1][(16+col)*520 + ko_]); \
  aZ = MFMA_(AH_, bh_, aZ, 0,0,0); \
  aZ = MFMA_(AL_, bh_, aZ, 0,0,0); \
  aZ = MFMA_(AH_, bl_, aZ, 0,0,0); \
  bh_ = *(const short8*)(&S2.whh[0][(32+col)*520 + ko_]); \
  bl_ = *(const short8*)(&S2.whh[1][(32+col)*520 + ko_]); \
  aNh = MFMA_(AH_, bh_, aNh, 0,0,0); \
  aNh = MFMA_(AL_, bh_, aNh, 0,0,0); \
  aNh = MFMA_(AH_, bl_, aNh, 0,0,0); }

#define GI1(i) { \
  short8 AH_ = __builtin_bit_cast(short8, ga##i); \
  const int ko_ = kq + (i)*32 + q*8; \
  short8 bh_ = *(const short8*)(&S2.wih[(col)*520 + ko_]); \
  aR = MFMA_(AH_, bh_, aR, 0,0,0); \
  bh_ = *(const short8*)(&S2.wih[(16+col)*520 + ko_]); \
  aZ = MFMA_(AH_, bh_, aZ, 0,0,0); \
  bh_ = *(const short8*)(&S2.wih[(32+col)*520 + ko_]); \
  aNi = MFMA_(AH_, bh_, aNi, 0,0,0); }

// ---------------- role3: k-half hi A, hi/lo B -----------------------------
#define DECL_HI8(P) \
  uint4v ha0,ha1,ha2,ha3,ha4,ha5,ha6,ha7; \
  LD4A(ha0,P,aoff8+0*32) LD4A(ha1,P,aoff8+1*32) LD4A(ha2,P,aoff8+2*32) LD4A(ha3,P,aoff8+3*32) \
  LD4A(ha4,P,aoff8+4*32) LD4A(ha5,P,aoff8+5*32) LD4A(ha6,P,aoff8+6*32) LD4A(ha7,P,aoff8+7*32) \
  VMBAR8(ha0,ha1,ha2,ha3,ha4,ha5,ha6,ha7)

#define MS1H(i) { \
  short8 AH_ = __builtin_bit_cast(short8, ha##i); \
  const int ko_ = kb + (i)*32 + q*8; \
  short8 bh_ = *(const short8*)(&S3.wpl[0][(col)*520 + ko_]); \
  short8 bl_ = *(const short8*)(&S3.wpl[1][(col)*520 + ko_]); \
  acc0 = MFMA_(AH_, bh_, acc0, 0,0,0); \
  acc0 = MFMA_(AH_, bl_, acc0, 0,0,0); }

#define RUN16(M) M(0) M(1) M(2) M(3) M(4) M(5) M(6) M(7) \
                 M(8) M(9) M(10) M(11) M(12) M(13) M(14) M(15)
#define RUN8(M)  M(0) M(1) M(2) M(3) M(4) M(5) M(6) M(7)
#define RUN4(M)  M(0) M(1) M(2) M(3)

extern "C" __global__ void __launch_bounds__(NT, 1)
decoder_rnn(const float* __restrict__ ctx,   // [64][512]
            const float* __restrict__ Wih0,  // [1536][513] (row stride 513!)
            const float* __restrict__ Whh0,
            const float* __restrict__ bih0,
            const float* __restrict__ bhh0g,
            const float* __restrict__ Wih1,
            const float* __restrict__ Whh1,
            const float* __restrict__ bih1g,
            const float* __restrict__ bhh1g,
            const float* __restrict__ Wo1,
            const float* __restrict__ bo1g,
            const float* __restrict__ Wo2,
            const float* __restrict__ bo2g,
            float* __restrict__ out,         // [64*1024 y][65536 h_i]
            float* __restrict__ ws)
{
  extern __shared__ char smem_raw[];
  SmemR0& S0 = *reinterpret_cast<SmemR0*>(smem_raw);
  SmemR2& S2 = *reinterpret_cast<SmemR2*>(smem_raw);
  SmemR3& S3 = *reinterpret_cast<SmemR3*>(smem_raw);
  const int tid = threadIdx.x;
  const int wg  = blockIdx.x;

  ushort* hp  = (ushort*)ws;                 // h0hi[2]@0/32768, h0lo[2]@65536/
                                             // 98304, h1hi@131072, h1lo@163840
  float* yout = (float*)ws + 196608;         // 2 x 2048
  int*  ibase = (int*)((float*)ws + 200704);
  int* gslots = ibase;                       // [256] gbar
  int* epoch  = ibase + 256;

  const float bo2v = bo2g[0];

  // ---------------- init (swaps -> LLC; once, off critical path) ----------
  for (int i = wg*NT + tid; i < 200704; i += NWG*NT)
    SWP((uint*)ws + i, 0u);

  const int gid   = wg >> 7;                 // 2 independent 32-batch machines
  const int m     = wg & 127;
  const int bbase = 32*gid;
  int role, j, bh = 0;
  if (m < 32){ role = 0; j = m; }
  else if (m < 96){ role = 2; bh = (m - 32) >> 5; j = m & 31; }
  else { role = 3; j = m - 96; }

  if (role == 0){
    for (int i = tid; i < 48*512; i += NT){
      int r = i >> 9, k = i & 511;
      int g3 = r >> 4, n = r & 15;
      float wv = Whh0[(size_t)(g3*512 + 16*j + n)*512 + k];
      ushort hh = bfrnd(wv);
      S0.wpl[0][r*520 + k] = hh;
      S0.wpl[1][r*520 + k] = bfrnd(wv - bf2f(hh));
    }
    if (tid < 48){
      int g3 = tid >> 4, n = tid & 15;
      S0.wcol[g3][n] = Wih0[(size_t)(g3*512 + 16*j + n)*513 + 512];
    }
    if (tid < 16) S0.bhnN[tid] = bhh0g[2*512 + 16*j + tid];
    for (int idx = tid; idx < 1536; idx += NT){   // 48 rows x 32 local b
      int r = idx >> 5, bl = idx & 31;
      int g3 = r >> 4, n = r & 15;
      int grow = g3*512 + 16*j + n;
      const float* wr = Wih0 + (size_t)grow*513;
      const float* cx = ctx  + (size_t)(bbase + bl)*512;
      float s = bih0[grow];
      if (g3 < 2) s += bhh0g[grow];
      #pragma unroll 4
      for (int k = 0; k < 512; ++k) s += wr[k]*cx[k];
      S0.gictx[g3*1088 + n*68 + bl] = s;
    }
  } else if (role == 2){
    for (int i = tid; i < 48*512; i += NT){
      int r = i >> 9, k = i & 511;
      int g3 = r >> 4, n = r & 15;
      size_t row = (size_t)(g3*512 + 16*j + n)*512 + k;
      float wv = Whh1[row];
      ushort hh = bfrnd(wv);
      S2.whh[0][r*520 + k] = hh;
      S2.whh[1][r*520 + k] = bfrnd(wv - bf2f(hh));
      S2.wih[r*520 + k] = bfrnd(Wih1[row]);       // HI ONLY
    }
    if (tid < 16){
      int n = tid;
      S2.bsumR[n] = bih1g[16*j + n]       + bhh1g[16*j + n];
      S2.bsumZ[n] = bih1g[512 + 16*j + n] + bhh1g[512 + 16*j + n];
      S2.binN[n]  = bih1g[1024 + 16*j + n];
      S2.bhnN[n]  = bhh1g[1024 + 16*j + n];
    }
  } else {
    for (int i = tid; i < 16*512; i += NT){
      int r = i >> 9, k = i & 511;
      float wv = Wo1[(size_t)(16*j + r)*512 + k];
      ushort hh = bfrnd(wv);
      S3.wpl[0][r*520 + k] = hh;
      S3.wpl[1][r*520 + k] = bfrnd(wv - bf2f(hh));
    }
    if (tid < 16){ S3.bo1v[tid] = bo1g[16*j + tid]; S3.wo2v[tid] = Wo2[16*j + tid]; }
  }

  gbar(gslots, epoch, wg, tid, 1);

  const int v   = tid >> 6;
  const int l   = tid & 63;
  const int q   = l >> 4;
  const int col = l & 15;
  const int ng  = 16*j + col;

  if (role == 0){
    const int bblk  = v & 1;
    const int aoffB = (bbase + 16*bblk + col)*512 + q*8;
    const int b0wL  = 16*bblk + 4*q;
    float hc0 = 0.f, hc1 = 0.f, hc2 = 0.f, hc3 = 0.f;
    for (int t = 0; t < TT; ++t){
      const int r0 = t & 1, w0 = r0 ^ 1;
      const ushort* rH = hp + r0*32768;
      const ushort* rL = hp + 65536 + r0*32768;
      ushort*       wH = hp + w0*32768;
      ushort*       wL = hp + 65536 + w0*32768;
      const uint emh = (t==0) ? 0u : (((((t-1)>>1)&1u)^1u) * TAGM);
      waitcan(rH + (size_t)bbase*512, emh, tid);     // h0[t-1] canary
      f32x4 acc0={0,0,0,0}, acc1={0,0,0,0}, acc2={0,0,0,0};
      if (v < 2){
        const uint em_ = emh;
        for(;;){
          DECL_HILO(rH, rL)
          uint fo_ = 0u;
          FOLD16(ha) FOLD16(la)
          if (__all((int)(fo_ == 0u))){ RUN16(MS3F) break; }
          __builtin_amdgcn_s_sleep(1);
        }
      }
      if (t > 0)                                     // y[t-1] canary
        waitcany(yout + ((t-1)&1)*2048 + bbase, (((t-1)>>1)&1u)^1u, tid);
      if (v == 0){
        float s = 0.f;
        if (t > 0){
          const uint ey_ = (((t-1)>>1)&1u)^1u;
          const float* yp = yout + ((t-1)&1)*2048 + bbase + l;
          for(;;){
            float vv[32]; uint fo_ = 0u;
            if (l < 32){
              #pragma unroll
              for (int jj = 0; jj < 32; ++jj)
                LD1SCD(vv[jj], yp + jj*64)
              VMBAR8(vv[0],vv[1],vv[2],vv[3],vv[4],vv[5],vv[6],vv[7])
              VMBAR8(vv[8],vv[9],vv[10],vv[11],vv[12],vv[13],vv[14],vv[15])
              VMBAR8(vv[16],vv[17],vv[18],vv[19],vv[20],vv[21],vv[22],vv[23])
              VMBAR8(vv[24],vv[25],vv[26],vv[27],vv[28],vv[29],vv[30],vv[31])
              #pragma unroll
              for (int jj = 0; jj < 32; ++jj)
                fo_ |= (__float_as_uint(vv[jj]) ^ ey_) & 1u;
            }
            if (__all((int)(fo_ == 0u))){
              if (l < 32){
                #pragma unroll
                for (int st = 16; st >= 1; st >>= 1)
                  #pragma unroll
                  for (int k2 = 0; k2 < st; ++k2) vv[k2] += vv[k2 + st];
                s = vv[0];
              }
              break;
            }
            __builtin_amdgcn_s_sleep(1);
          }
        }
        if (l < 32){
          float pv = fmaxf(s + bo2v, 0.f);
          S0.prevS[l] = pv;
          if (j == 0 && t > 0) out[(size_t)(bbase + l)*TT + (t-1)] = pv;
        }
      }
      __syncthreads();
      if (v < 2){
        const uint tg0_ = ((t>>1)&1u)^1u;
        f32x4 pv4 = *(const f32x4*)&S0.prevS[b0wL];
        f32x4 gR = *(const f32x4*)&S0.gictx[0*1088 + col*68 + b0wL];
        f32x4 gZ = *(const f32x4*)&S0.gictx[1*1088 + col*68 + b0wL];
        f32x4 gN = *(const f32x4*)&S0.gictx[2*1088 + col*68 + b0wL];
        float wc0 = S0.wcol[0][col], wc1 = S0.wcol[1][col], wc2 = S0.wcol[2][col];
        float bhn = S0.bhnN[col];
        #define E0(i, HC) { \
          float rr = sigm(gR[i] + pv4[i]*wc0 + acc0[i]); \
          float zz = sigm(gZ[i] + pv4[i]*wc1 + acc1[i]); \
          float nn = tanh_f(gN[i] + pv4[i]*wc2 + rr*(acc2[i] + bhn)); \
          float h = (1.f-zz)*nn + zz*HC; \
          HC = h; \
          uint hu_ = ((uint)bfrnd(h) & 0xFFFEu) | tg0_; \
          uint lu_ = ((uint)bfrnd(h - bf2f((ushort)hu_)) & 0xFFFEu) | tg0_; \
          STSH(wH + (size_t)(bbase + b0wL + (i))*512 + ng, hu_) \
          STSH(wL + (size_t)(bbase + b0wL + (i))*512 + ng, lu_) }
        E0(0,hc0) E0(1,hc1) E0(2,hc2) E0(3,hc3)
        #undef E0
      }
      // stores issued; consumers detect via data tags (no flag, no drain)
    }
  } else if (role == 2){
    ushort* p1H = hp + 131072;
    ushort* p1L = hp + 163840;
    const int bb16  = bbase + 16*bh;
    const int kq    = v*128;                 // k-quarter per wave
    const int aoffA = (bb16 + col)*512 + kq + q*8;
    float hc0 = 0.f, hc1 = 0.f, hc2 = 0.f, hc3 = 0.f;   // wave0: batches 4q+i
    for (int t = 0; t < TT; ++t){
      // -------- phase A (slack-funded): gh1 = Whh1 @ h1[t-1], full prec ----
      const uint emA = (t==0) ? 0u : ((((t-1)&1u)^1u) * TAGM);
      waitcan(p1H + (size_t)bb16*512, emA, tid);     // own-half h1[t-1] canary
      f32x4 aR={0,0,0,0}, aZ={0,0,0,0}, aNi={0,0,0,0}, aNh={0,0,0,0};
      {
        const uint em_ = emA;
        for(;;){
          uint4v ha0,ha1,ha2,ha3, la0,la1,la2,la3;
          LD4A(ha0, p1H, aoffA+0*32) LD4A(ha1, p1H, aoffA+1*32)
          LD4A(ha2, p1H, aoffA+2*32) LD4A(ha3, p1H, aoffA+3*32)
          LD4A(la0, p1L, aoffA+0*32) LD4A(la1, p1L, aoffA+1*32)
          LD4A(la2, p1L, aoffA+2*32) LD4A(la3, p1L, aoffA+3*32)
          VMBAR8(ha0,ha1,ha2,ha3,la0,la1,la2,la3)
          uint fo_ = 0u;
          FOLD4(ha) FOLD4(la)
          if (__all((int)(fo_ == 0u))){ RUN4(GH1) break; }
          __builtin_amdgcn_s_sleep(1);
        }
      }
      // -------- phase B (critical): gi = Wih1_hi @ h0hi[t] ----------------
      const ushort* rH = hp + ((t & 1) ^ 1)*32768;
      const uint emB = (((t>>1)&1u)^1u) * TAGM;
      waitcan(rH + (size_t)bb16*512, emB, tid);      // h0[t] canary
      {
        const uint em_ = emB;
        for(;;){
          uint4v ga0,ga1,ga2,ga3;
          LD4A(ga0, rH, aoffA+0*32) LD4A(ga1, rH, aoffA+1*32)
          LD4A(ga2, rH, aoffA+2*32) LD4A(ga3, rH, aoffA+3*32)
          VMBAR4(ga0,ga1,ga2,ga3)
          uint fo_ = 0u;
          FOLD4(ga)
          if (__all((int)(fo_ == 0u))){ RUN4(GI1) break; }
          __builtin_amdgcn_s_sleep(1);
        }
      }
      // -------- combine k-quarters, EW, store -----------------------------
      if (v >= 1){
        *(f32x4*)&S2.xk[v-1][l][0]  = aR;
        *(f32x4*)&S2.xk[v-1][l][4]  = aZ;
        *(f32x4*)&S2.xk[v-1][l][8]  = aNi;
        *(f32x4*)&S2.xk[v-1][l][12] = aNh;
      }
      __syncthreads();
      if (v == 0){
        const uint tg1_ = (t&1u)^1u;
        #pragma unroll
        for (int w = 0; w < 3; ++w){
          aR  += *(const f32x4*)&S2.xk[w][l][0];
          aZ  += *(const f32x4*)&S2.xk[w][l][4];
          aNi += *(const f32x4*)&S2.xk[w][l][8];
          aNh += *(const f32x4*)&S2.xk[w][l][12];
        }
        float bsR = S2.bsumR[col], bsZ = S2.bsumZ[col];
        float biN = S2.binN[col],  bhN = S2.bhnN[col];
        #define E1(i, HC) { \
          float r1 = sigm(aR[i] + bsR); \
          float z1 = sigm(aZ[i] + bsZ); \
          float n1 = tanh_f(aNi[i] + biN + r1*(aNh[i] + bhN)); \
          float h = (1.f-z1)*n1 + z1*HC; \
          HC = h; \
          uint hu_ = ((uint)bfrnd(h) & 0xFFFEu) | tg1_; \
          uint lu_ = ((uint)bfrnd(h - bf2f((ushort)hu_)) & 0xFFFEu) | tg1_; \
          STSH(p1H + (size_t)(bb16 + 4*q + (i))*512 + ng, hu_) \
          STSH(p1L + (size_t)(bb16 + 4*q + (i))*512 + ng, lu_) }
        E1(0,hc0) E1(1,hc1) E1(2,hc2) E1(3,hc3)
        #undef E1
      }
      __syncthreads();                       // xk buffer reuse fence
    }
  } else {
    const ushort* rH = hp + 131072;          // h1 hi plane ONLY (critical)
    const int bblk  = v & 1;
    const int kb    = (v >> 1)*256;
    const int aoff8 = (bbase + 16*bblk + col)*512 + kb + q*8;
    const int b0wL  = 16*bblk + 4*q;
    for (int t = 0; t < TT; ++t){
      const uint emh1 = ((t&1u)^1u) * TAGM;
      waitcan2(rH + (size_t)bbase*512, rH + (size_t)(bbase+16)*512, emh1, tid);
      f32x4 acc0={0,0,0,0};
      {
        const uint em_ = emh1;
        for(;;){
          DECL_HI8(rH)
          uint fo_ = 0u;
          FOLD8(ha)
          if (__all((int)(fo_ == 0u))){ RUN8(MS1H) break; }
          __builtin_amdgcn_s_sleep(1);
        }
      }
      if (v >= 2)
        *(f32x4*)&S3.xk[bblk][l][0] = acc0;
      __syncthreads();
      if (v < 2){
        acc0 += *(const f32x4*)&S3.xk[bblk][l][0];
        float s0 = S3.wo2v[col]*fmaxf(acc0[0] + S3.bo1v[col], 0.f);
        float s1 = S3.wo2v[col]*fmaxf(acc0[1] + S3.bo1v[col], 0.f);
        float s2 = S3.wo2v[col]*fmaxf(acc0[2] + S3.bo1v[col], 0.f);
        float s3 = S3.wo2v[col]*fmaxf(acc0[3] + S3.bo1v[col], 0.f);
        #pragma unroll
        for (int d = 1; d < 16; d <<= 1){
          s0 += __shfl_xor(s0, d);
          s1 += __shfl_xor(s1, d);
          s2 += __shfl_xor(s2, d);
          s3 += __shfl_xor(s3, d);
        }
        if (col == 0){
          const uint tgy_ = ((t>>1)&1u)^1u;
          uint* rp = (uint*)(yout + (t&1)*2048 + j*64 + bbase + b0wL);
          uint4v uv = { (__float_as_uint(s0) & ~1u) | tgy_,
                        (__float_as_uint(s1) & ~1u) | tgy_,
                        (__float_as_uint(s2) & ~1u) | tgy_,
                        (__float_as_uint(s3) & ~1u) | tgy_ };
          ST4SC(rp, uv)
        }
      }
      __syncthreads();                       // xk buffer reuse fence
    }
  }

  // ---------------- finale: drain once, then global barrier ---------------
  drain_sync();
  gbar(gslots, epoch, wg, tid, 2);
  if (wg == 0 && tid < 64){
    float s = 0.f;
    const float* yp = yout + 2048 + tid;     // parity of t=1023 is 1
    #pragma unroll
    for (int jj = 0; jj < 32; ++jj) s += ALDF(yp + jj*64);
    out[(size_t)tid*TT + 1023] = fmaxf(s + bo2v, 0.f);
  }
  {
    int g = wg*256 + tid;                    // 256 WGs x 256 thr = 65536
    if (g < 32768) out[65536 + g] = bf2f(hp[g]) + bf2f(hp[65536 + g]);
    else {
      int g2 = g - 32768;
      out[65536 + g] = bf2f(hp[131072 + g2]) + bf2f(hp[163840 + g2]);
    }
  }
}

extern "C" void kernel_launch(void* const* d_in, const int* in_sizes, int n_in,
                              void* d_out, int out_size, void* d_ws, size_t ws_size,
                              hipStream_t stream){
  const float* ctx   = (const float*)d_in[0];
  const float* Wih0  = (const float*)d_in[2];
  const float* Whh0  = (const float*)d_in[3];
  const float* bih0  = (const float*)d_in[4];
  const float* bhh0  = (const float*)d_in[5];
  const float* Wih1  = (const float*)d_in[6];
  const float* Whh1  = (const float*)d_in[7];
  const float* bih1  = (const float*)d_in[8];
  const float* bhh1  = (const float*)d_in[9];
  const float* Wo1   = (const float*)d_in[10];
  const float* bo1   = (const float*)d_in[11];
  const float* Wo2   = (const float*)d_in[12];
  const float* bo2   = (const float*)d_in[13];

  (void)in_sizes; (void)n_in; (void)out_size; (void)ws_size;

  const int smem_sz = (int)sizeof(SmemR2);   // largest overlay (162,304 B)
  (void)hipFuncSetAttribute((const void*)decoder_rnn,
                            hipFuncAttributeMaxDynamicSharedMemorySize,
                            smem_sz);

  decoder_rnn<<<NWG, NT, smem_sz, stream>>>(
      ctx, Wih0, Whh0, bih0, bhh0, Wih1, Whh1, bih1, bhh1,
      Wo1, bo1, Wo2, bo2, (float*)d_out, (float*)d_ws);
}

// Round 14
// 7316.724 us; speedup vs baseline: 1.4421x; 1.1340x over previous
//
#include <hip/hip_runtime.h>
#include <stdint.h>

// DecoderRNN R29: R28 base (8.30ms) + two detect-path trims:
//  (1) role0's y hop: idle wave2 spins DIRECTLY on the y-partial data
//      (32 dwords, bit0 tag validation, s_sleep-paced) in parallel with
//      waves0/1's h0 MFMA -> detection happens ON the data, saving the
//      canary->load serialization (~1 RTT) on the critical y tail.
//      Poll addresses span 64 lines (~16 pollers/line; R24's hotspot was
//      same-line concentration, avoided here).
//  (2) DUAL canaries everywhere: poll producer j=0's AND j=31's 16B slices
//      in one 2-request batch (distinct lines) -> straggler retries cut.
//  prevS hazard (wave2 writes / waves0-1 read): ordered by the h0-canary
//  syncthreads of the NEXT iteration -> safe.
// Everything else byte-identical to R28 (tagged planes, no flags, no
// producer drains, role1 eliminated, role2 x64 4-way K-split, Wih1 hi-only).

#define NWG 256
#define NT  256
#define TT  1024

typedef unsigned short ushort;
typedef unsigned int   uint;
typedef __attribute__((ext_vector_type(8))) short short8;
typedef __attribute__((ext_vector_type(4))) float f32x4;
typedef __attribute__((ext_vector_type(4))) uint  uint4v;

struct __align__(16) SmemR0 {
  ushort wpl[2][48*520];     // Whh0 hi/lo
  float  gictx[3*16*68];
  float  wcol[3][16];
  float  bhnN[16];
  float  prevS[64];          // [0..32) used
};
struct __align__(16) SmemR2 {
  ushort whh[2][48*520];     // Whh1 hi/lo (full precision, self-recurrence)
  ushort wih[48*520];        // Wih1 HI ONLY (critical path)
  float  xk[3][64][16];      // k-quarter combine: {R,Z,Ni,Nh} x4
  float  bsumR[16], bsumZ[16], binN[16], bhnN[16];
};
struct __align__(16) SmemR3 {
  ushort wpl[2][16*520];     // Wo1 block hi/lo
  float  xk[2][64][4];
  float  bo1v[16], wo2v[16];
};

__device__ __forceinline__ float frcp(float x){
#if __has_builtin(__builtin_amdgcn_rcpf)
  return __builtin_amdgcn_rcpf(x);
#else
  return 1.f/x;
#endif
}
__device__ __forceinline__ float sigm(float x){ return frcp(1.f + __expf(-x)); }
__device__ __forceinline__ float tanh_f(float x){
  return 1.f - 2.f*frcp(__expf(2.f*x) + 1.f);
}
__device__ __forceinline__ float bf2f(ushort h){ return __uint_as_float(((uint)h)<<16); }
__device__ __forceinline__ ushort bfrnd(float x){
  uint u = __float_as_uint(x);
  return (ushort)((u + 0x7fffu + ((u>>16)&1u)) >> 16);
}
#define SWP(p, v)  (void)__hip_atomic_exchange((uint*)(p), (uint)(v), __ATOMIC_RELAXED, __HIP_MEMORY_SCOPE_AGENT)
#define ALD1(p)    __hip_atomic_load((const uint*)(p), __ATOMIC_RELAXED, __HIP_MEMORY_SCOPE_AGENT)
#define ALDF(p)    __uint_as_float(ALD1(p))

__device__ __forceinline__ void gbar(int* slots, int* epoch, int w, int tid, int e){
  __syncthreads();
  if (tid == 0)
    __hip_atomic_store(&slots[w], e, __ATOMIC_RELEASE, __HIP_MEMORY_SCOPE_AGENT);
  if (w == 0 && tid < 64){
    for(;;){
      int m0 = __hip_atomic_load(&slots[tid*4+0], __ATOMIC_RELAXED, __HIP_MEMORY_SCOPE_AGENT);
      int m1 = __hip_atomic_load(&slots[tid*4+1], __ATOMIC_RELAXED, __HIP_MEMORY_SCOPE_AGENT);
      int m2 = __hip_atomic_load(&slots[tid*4+2], __ATOMIC_RELAXED, __HIP_MEMORY_SCOPE_AGENT);
      int m3 = __hip_atomic_load(&slots[tid*4+3], __ATOMIC_RELAXED, __HIP_MEMORY_SCOPE_AGENT);
      if (__all(min(min(m0,m1),min(m2,m3)) >= e)) break;
      __builtin_amdgcn_s_sleep(1);
    }
    if (tid == 0){
      __builtin_amdgcn_fence(__ATOMIC_ACQUIRE, "agent");
      __hip_atomic_store(epoch, e, __ATOMIC_RELEASE, __HIP_MEMORY_SCOPE_AGENT);
    }
  }
  if (tid == 0){
    while (__hip_atomic_load(epoch, __ATOMIC_RELAXED, __HIP_MEMORY_SCOPE_AGENT) < e)
      __builtin_amdgcn_s_sleep(1);
    __builtin_amdgcn_fence(__ATOMIC_ACQUIRE, "agent");
  }
  __syncthreads();
}

__device__ __forceinline__ void drain_sync(){
  __builtin_amdgcn_s_waitcnt(0);
  __syncthreads();
}

// coherent LLC-direct ops (sc0 sc1 = bypass L1+L2, coalesced)
#define LD1SCD(dst, addr) \
  asm volatile("global_load_dword %0, %1, off sc0 sc1" : "=v"(dst) : "v"(addr));
#define STSH(addr, val) \
  asm volatile("global_store_short %0, %1, off sc0 sc1" :: "v"(addr), "v"(val) : "memory");
#define ST4SC(addr, val) \
  asm volatile("global_store_dwordx4 %0, %1, off sc0 sc1" :: "v"(addr), "v"(val) : "memory");
#define LD4A(DST, P, OFS) \
  asm volatile("global_load_dwordx4 %0, %1, off sc0 sc1" : "=v"(DST) : "v"((P) + (OFS)));
#define VMBAR2(a,b) asm volatile("s_waitcnt vmcnt(0)" : "+v"(a),"+v"(b));
#define VMBAR4(a,b,c,d) \
  asm volatile("s_waitcnt vmcnt(0)" : "+v"(a),"+v"(b),"+v"(c),"+v"(d));
#define VMBAR8(a,b,c,d,e,f,g,h) \
  asm volatile("s_waitcnt vmcnt(0)" \
               : "+v"(a),"+v"(b),"+v"(c),"+v"(d),"+v"(e),"+v"(f),"+v"(g),"+v"(h));

// ---- tag machinery --------------------------------------------------------
#define TAGM 0x00010001u
#define FOLDV(V) fo_ |= ((V.x^em_)&TAGM)|((V.y^em_)&TAGM)| \
                        ((V.z^em_)&TAGM)|((V.w^em_)&TAGM);
#define FOLD4(p)  FOLDV(p##0) FOLDV(p##1) FOLDV(p##2) FOLDV(p##3)
#define FOLD8(p)  FOLD4(p) FOLDV(p##4) FOLDV(p##5) FOLDV(p##6) FOLDV(p##7)
#define FOLD16(p) FOLD8(p) FOLDV(p##8) FOLDV(p##9) FOLDV(p##10) FOLDV(p##11) \
                  FOLDV(p##12) FOLDV(p##13) FOLDV(p##14) FOLDV(p##15)

// dual canary poll: tid0 loads two 16B sites (distinct lines) per iteration
__device__ __forceinline__ void waitcan2(const ushort* pa, const ushort* pb,
                                         uint em, int tid){
  if (tid == 0){
    for(;;){
      uint4v a, b;
      LD4A(a, (const uint*)pa, 0)
      LD4A(b, (const uint*)pb, 0)
      VMBAR2(a, b)
      uint fo = ((a.x^em)&TAGM)|((a.y^em)&TAGM)|((a.z^em)&TAGM)|((a.w^em)&TAGM)
              | ((b.x^em)&TAGM)|((b.y^em)&TAGM)|((b.z^em)&TAGM)|((b.w^em)&TAGM);
      if (fo == 0u) break;
    }
  }
  __syncthreads();
}

#define MFMA_ __builtin_amdgcn_mfma_f32_16x16x32_bf16

// ---------------- role0: full-K hi/lo (waves 0,1) ----------------
#define DECL_HILO(PH, PL) \
  uint4v ha0,ha1,ha2,ha3,ha4,ha5,ha6,ha7,ha8,ha9,ha10,ha11,ha12,ha13,ha14,ha15; \
  uint4v la0,la1,la2,la3,la4,la5,la6,la7,la8,la9,la10,la11,la12,la13,la14,la15; \
  LD4A(ha0,PH,aoffB+0*32) LD4A(ha1,PH,aoffB+1*32) LD4A(ha2,PH,aoffB+2*32) LD4A(ha3,PH,aoffB+3*32) \
  LD4A(ha4,PH,aoffB+4*32) LD4A(ha5,PH,aoffB+5*32) LD4A(ha6,PH,aoffB+6*32) LD4A(ha7,PH,aoffB+7*32) \
  LD4A(ha8,PH,aoffB+8*32) LD4A(ha9,PH,aoffB+9*32) LD4A(ha10,PH,aoffB+10*32) LD4A(ha11,PH,aoffB+11*32) \
  LD4A(ha12,PH,aoffB+12*32) LD4A(ha13,PH,aoffB+13*32) LD4A(ha14,PH,aoffB+14*32) LD4A(ha15,PH,aoffB+15*32) \
  LD4A(la0,PL,aoffB+0*32) LD4A(la1,PL,aoffB+1*32) LD4A(la2,PL,aoffB+2*32) LD4A(la3,PL,aoffB+3*32) \
  LD4A(la4,PL,aoffB+4*32) LD4A(la5,PL,aoffB+5*32) LD4A(la6,PL,aoffB+6*32) LD4A(la7,PL,aoffB+7*32) \
  LD4A(la8,PL,aoffB+8*32) LD4A(la9,PL,aoffB+9*32) LD4A(la10,PL,aoffB+10*32) LD4A(la11,PL,aoffB+11*32) \
  LD4A(la12,PL,aoffB+12*32) LD4A(la13,PL,aoffB+13*32) LD4A(la14,PL,aoffB+14*32) LD4A(la15,PL,aoffB+15*32) \
  VMBAR8(ha0,ha1,ha2,ha3,ha4,ha5,ha6,ha7) \
  VMBAR8(ha8,ha9,ha10,ha11,ha12,ha13,ha14,ha15) \
  VMBAR8(la0,la1,la2,la3,la4,la5,la6,la7) \
  VMBAR8(la8,la9,la10,la11,la12,la13,la14,la15)

#define MS3F(i) { \
  short8 AH_ = __builtin_bit_cast(short8, ha##i); \
  short8 AL_ = __builtin_bit_cast(short8, la##i); \
  const int ko_ = (i)*32 + q*8; \
  short8 bh_ = *(const short8*)(&S0.wpl[0][(col)*520 + ko_]); \
  short8 bl_ = *(const short8*)(&S0.wpl[1][(col)*520 + ko_]); \
  acc0 = MFMA_(AH_, bh_, acc0, 0,0,0); \
  acc0 = MFMA_(AL_, bh_, acc0, 0,0,0); \
  acc0 = MFMA_(AH_, bl_, acc0, 0,0,0); \
  bh_ = *(const short8*)(&S0.wpl[0][(16+col)*520 + ko_]); \
  bl_ = *(const short8*)(&S0.wpl[1][(16+col)*520 + ko_]); \
  acc1 = MFMA_(AH_, bh_, acc1, 0,0,0); \
  acc1 = MFMA_(AL_, bh_, acc1, 0,0,0); \
  acc1 = MFMA_(AH_, bl_, acc1, 0,0,0); \
  bh_ = *(const short8*)(&S0.wpl[0][(32+col)*520 + ko_]); \
  bl_ = *(const short8*)(&S0.wpl[1][(32+col)*520 + ko_]); \
  acc2 = MFMA_(AH_, bh_, acc2, 0,0,0); \
  acc2 = MFMA_(AL_, bh_, acc2, 0,0,0); \
  acc2 = MFMA_(AH_, bl_, acc2, 0,0,0); }

// ---------------- role2: gh1 full (hi/lo A,B) + gi (hi A, hi B) ----------
#define GH1(i) { \
  short8 AH_ = __builtin_bit_cast(short8, ha##i); \
  short8 AL_ = __builtin_bit_cast(short8, la##i); \
  const int ko_ = kq + (i)*32 + q*8; \
  short8 bh_ = *(const short8*)(&S2.whh[0][(col)*520 + ko_]); \
  short8 bl_ = *(const short8*)(&S2.whh[1][(col)*520 + ko_]); \
  aR = MFMA_(AH_, bh_, aR, 0,0,0); \
  aR = MFMA_(AL_, bh_, aR, 0,0,0); \
  aR = MFMA_(AH_, bl_, aR, 0,0,0); \
  bh_ = *(const short8*)(&S2.whh[0][(16+col)*520 + ko_]); \
  bl_ = *(const short8*)(&S2.whh[1][(16+col)*520 + ko_]); \
  aZ = MFMA_(AH_, bh_, aZ, 0,0,0); \
  aZ = MFMA_(AL_, bh_, aZ, 0,0,0); \
  aZ = MFMA_(AH_, bl_, aZ, 0,0,0); \
  bh_ = *(const short8*)(&S2.whh[0][(32+col)*520 + ko_]); \
  bl_ = *(const short8*)(&S2.whh[1][(32+col)*520 + ko_]); \
  aNh = MFMA_(AH_, bh_, aNh, 0,0,0); \
  aNh = MFMA_(AL_, bh_, aNh, 0,0,0); \
  aNh = MFMA_(AH_, bl_, aNh, 0,0,0); }

#define GI1(i) { \
  short8 AH_ = __builtin_bit_cast(short8, ga##i); \
  const int ko_ = kq + (i)*32 + q*8; \
  short8 bh_ = *(const short8*)(&S2.wih[(col)*520 + ko_]); \
  aR = MFMA_(AH_, bh_, aR, 0,0,0); \
  bh_ = *(const short8*)(&S2.wih[(16+col)*520 + ko_]); \
  aZ = MFMA_(AH_, bh_, aZ, 0,0,0); \
  bh_ = *(const short8*)(&S2.wih[(32+col)*520 + ko_]); \
  aNi = MFMA_(AH_, bh_, aNi, 0,0,0); }

// ---------------- role3: k-half hi A, hi/lo B -----------------------------
#define DECL_HI8(P) \
  uint4v ha0,ha1,ha2,ha3,ha4,ha5,ha6,ha7; \
  LD4A(ha0,P,aoff8+0*32) LD4A(ha1,P,aoff8+1*32) LD4A(ha2,P,aoff8+2*32) LD4A(ha3,P,aoff8+3*32) \
  LD4A(ha4,P,aoff8+4*32) LD4A(ha5,P,aoff8+5*32) LD4A(ha6,P,aoff8+6*32) LD4A(ha7,P,aoff8+7*32) \
  VMBAR8(ha0,ha1,ha2,ha3,ha4,ha5,ha6,ha7)

#define MS1H(i) { \
  short8 AH_ = __builtin_bit_cast(short8, ha##i); \
  const int ko_ = kb + (i)*32 + q*8; \
  short8 bh_ = *(const short8*)(&S3.wpl[0][(col)*520 + ko_]); \
  short8 bl_ = *(const short8*)(&S3.wpl[1][(col)*520 + ko_]); \
  acc0 = MFMA_(AH_, bh_, acc0, 0,0,0); \
  acc0 = MFMA_(AH_, bl_, acc0, 0,0,0); }

#define RUN16(M) M(0) M(1) M(2) M(3) M(4) M(5) M(6) M(7) \
                 M(8) M(9) M(10) M(11) M(12) M(13) M(14) M(15)
#define RUN8(M)  M(0) M(1) M(2) M(3) M(4) M(5) M(6) M(7)
#define RUN4(M)  M(0) M(1) M(2) M(3)

extern "C" __global__ void __launch_bounds__(NT, 1)
decoder_rnn(const float* __restrict__ ctx,   // [64][512]
            const float* __restrict__ Wih0,  // [1536][513] (row stride 513!)
            const float* __restrict__ Whh0,
            const float* __restrict__ bih0,
            const float* __restrict__ bhh0g,
            const float* __restrict__ Wih1,
            const float* __restrict__ Whh1,
            const float* __restrict__ bih1g,
            const float* __restrict__ bhh1g,
            const float* __restrict__ Wo1,
            const float* __restrict__ bo1g,
            const float* __restrict__ Wo2,
            const float* __restrict__ bo2g,
            float* __restrict__ out,         // [64*1024 y][65536 h_i]
            float* __restrict__ ws)
{
  extern __shared__ char smem_raw[];
  SmemR0& S0 = *reinterpret_cast<SmemR0*>(smem_raw);
  SmemR2& S2 = *reinterpret_cast<SmemR2*>(smem_raw);
  SmemR3& S3 = *reinterpret_cast<SmemR3*>(smem_raw);
  const int tid = threadIdx.x;
  const int wg  = blockIdx.x;

  ushort* hp  = (ushort*)ws;                 // h0hi[2]@0/32768, h0lo[2]@65536/
                                             // 98304, h1hi@131072, h1lo@163840
  float* yout = (float*)ws + 196608;         // 2 x 2048
  int*  ibase = (int*)((float*)ws + 200704);
  int* gslots = ibase;                       // [256] gbar
  int* epoch  = ibase + 256;

  const float bo2v = bo2g[0];

  // ---------------- init (swaps -> LLC; once, off critical path) ----------
  for (int i = wg*NT + tid; i < 200704; i += NWG*NT)
    SWP((uint*)ws + i, 0u);

  const int gid   = wg >> 7;                 // 2 independent 32-batch machines
  const int m     = wg & 127;
  const int bbase = 32*gid;
  int role, j, bh = 0;
  if (m < 32){ role = 0; j = m; }
  else if (m < 96){ role = 2; bh = (m - 32) >> 5; j = m & 31; }
  else { role = 3; j = m - 96; }

  if (role == 0){
    for (int i = tid; i < 48*512; i += NT){
      int r = i >> 9, k = i & 511;
      int g3 = r >> 4, n = r & 15;
      float wv = Whh0[(size_t)(g3*512 + 16*j + n)*512 + k];
      ushort hh = bfrnd(wv);
      S0.wpl[0][r*520 + k] = hh;
      S0.wpl[1][r*520 + k] = bfrnd(wv - bf2f(hh));
    }
    if (tid < 48){
      int g3 = tid >> 4, n = tid & 15;
      S0.wcol[g3][n] = Wih0[(size_t)(g3*512 + 16*j + n)*513 + 512];
    }
    if (tid < 16) S0.bhnN[tid] = bhh0g[2*512 + 16*j + tid];
    for (int idx = tid; idx < 1536; idx += NT){   // 48 rows x 32 local b
      int r = idx >> 5, bl = idx & 31;
      int g3 = r >> 4, n = r & 15;
      int grow = g3*512 + 16*j + n;
      const float* wr = Wih0 + (size_t)grow*513;
      const float* cx = ctx  + (size_t)(bbase + bl)*512;
      float s = bih0[grow];
      if (g3 < 2) s += bhh0g[grow];
      #pragma unroll 4
      for (int k = 0; k < 512; ++k) s += wr[k]*cx[k];
      S0.gictx[g3*1088 + n*68 + bl] = s;
    }
  } else if (role == 2){
    for (int i = tid; i < 48*512; i += NT){
      int r = i >> 9, k = i & 511;
      int g3 = r >> 4, n = r & 15;
      size_t row = (size_t)(g3*512 + 16*j + n)*512 + k;
      float wv = Whh1[row];
      ushort hh = bfrnd(wv);
      S2.whh[0][r*520 + k] = hh;
      S2.whh[1][r*520 + k] = bfrnd(wv - bf2f(hh));
      S2.wih[r*520 + k] = bfrnd(Wih1[row]);       // HI ONLY
    }
    if (tid < 16){
      int n = tid;
      S2.bsumR[n] = bih1g[16*j + n]       + bhh1g[16*j + n];
      S2.bsumZ[n] = bih1g[512 + 16*j + n] + bhh1g[512 + 16*j + n];
      S2.binN[n]  = bih1g[1024 + 16*j + n];
      S2.bhnN[n]  = bhh1g[1024 + 16*j + n];
    }
  } else {
    for (int i = tid; i < 16*512; i += NT){
      int r = i >> 9, k = i & 511;
      float wv = Wo1[(size_t)(16*j + r)*512 + k];
      ushort hh = bfrnd(wv);
      S3.wpl[0][r*520 + k] = hh;
      S3.wpl[1][r*520 + k] = bfrnd(wv - bf2f(hh));
    }
    if (tid < 16){ S3.bo1v[tid] = bo1g[16*j + tid]; S3.wo2v[tid] = Wo2[16*j + tid]; }
  }

  gbar(gslots, epoch, wg, tid, 1);

  const int v   = tid >> 6;
  const int l   = tid & 63;
  const int q   = l >> 4;
  const int col = l & 15;
  const int ng  = 16*j + col;

  if (role == 0){
    const int bblk  = v & 1;
    const int aoffB = (bbase + 16*bblk + col)*512 + q*8;
    const int b0wL  = 16*bblk + 4*q;
    float hc0 = 0.f, hc1 = 0.f, hc2 = 0.f, hc3 = 0.f;
    for (int t = 0; t < TT; ++t){
      const int r0 = t & 1, w0 = r0 ^ 1;
      const ushort* rH = hp + r0*32768;
      const ushort* rL = hp + 65536 + r0*32768;
      ushort*       wH = hp + w0*32768;
      ushort*       wL = hp + 65536 + w0*32768;
      const uint emh = (t==0) ? 0u : (((((t-1)>>1)&1u)^1u) * TAGM);
      // dual canary: j=0 slice (k=0) and j=31 slice (k=496) of row bbase
      waitcan2(rH + (size_t)bbase*512, rH + (size_t)bbase*512 + 496, emh, tid);
      f32x4 acc0={0,0,0,0}, acc1={0,0,0,0}, acc2={0,0,0,0};
      if (v < 2){
        const uint em_ = emh;
        for(;;){
          DECL_HILO(rH, rL)
          uint fo_ = 0u;
          FOLD16(ha) FOLD16(la)
          if (__all((int)(fo_ == 0u))){ RUN16(MS3F) break; }
          __builtin_amdgcn_s_sleep(1);
        }
      }
      if (v == 2){                           // y path: spin ON the data
        float s = 0.f;
        if (t > 0){
          const uint ey_ = (((t-1)>>1)&1u)^1u;
          const float* yp = yout + ((t-1)&1)*2048 + bbase + l;
          for(;;){
            float vv[32]; uint fo_ = 0u;
            if (l < 32){
              #pragma unroll
              for (int jj = 0; jj < 32; ++jj)
                LD1SCD(vv[jj], yp + jj*64)
              VMBAR8(vv[0],vv[1],vv[2],vv[3],vv[4],vv[5],vv[6],vv[7])
              VMBAR8(vv[8],vv[9],vv[10],vv[11],vv[12],vv[13],vv[14],vv[15])
              VMBAR8(vv[16],vv[17],vv[18],vv[19],vv[20],vv[21],vv[22],vv[23])
              VMBAR8(vv[24],vv[25],vv[26],vv[27],vv[28],vv[29],vv[30],vv[31])
              #pragma unroll
              for (int jj = 0; jj < 32; ++jj)
                fo_ |= (__float_as_uint(vv[jj]) ^ ey_) & 1u;
            }
            if (__all((int)(fo_ == 0u))){
              if (l < 32){
                #pragma unroll
                for (int st = 16; st >= 1; st >>= 1)
                  #pragma unroll
                  for (int k2 = 0; k2 < st; ++k2) vv[k2] += vv[k2 + st];
                s = vv[0];
              }
              break;
            }
            __builtin_amdgcn_s_sleep(1);
          }
        }
        if (l < 32){
          float pv = fmaxf(s + bo2v, 0.f);
          S0.prevS[l] = pv;
          if (j == 0 && t > 0) out[(size_t)(bbase + l)*TT + (t-1)] = pv;
        }
      }
      __syncthreads();
      if (v < 2){
        const uint tg0_ = ((t>>1)&1u)^1u;
        f32x4 pv4 = *(const f32x4*)&S0.prevS[b0wL];
        f32x4 gR = *(const f32x4*)&S0.gictx[0*1088 + col*68 + b0wL];
        f32x4 gZ = *(const f32x4*)&S0.gictx[1*1088 + col*68 + b0wL];
        f32x4 gN = *(const f32x4*)&S0.gictx[2*1088 + col*68 + b0wL];
        float wc0 = S0.wcol[0][col], wc1 = S0.wcol[1][col], wc2 = S0.wcol[2][col];
        float bhn = S0.bhnN[col];
        #define E0(i, HC) { \
          float rr = sigm(gR[i] + pv4[i]*wc0 + acc0[i]); \
          float zz = sigm(gZ[i] + pv4[i]*wc1 + acc1[i]); \
          float nn = tanh_f(gN[i] + pv4[i]*wc2 + rr*(acc2[i] + bhn)); \
          float h = (1.f-zz)*nn + zz*HC; \
          HC = h; \
          uint hu_ = ((uint)bfrnd(h) & 0xFFFEu) | tg0_; \
          uint lu_ = ((uint)bfrnd(h - bf2f((ushort)hu_)) & 0xFFFEu) | tg0_; \
          STSH(wH + (size_t)(bbase + b0wL + (i))*512 + ng, hu_) \
          STSH(wL + (size_t)(bbase + b0wL + (i))*512 + ng, lu_) }
        E0(0,hc0) E0(1,hc1) E0(2,hc2) E0(3,hc3)
        #undef E0
      }
      // stores issued; consumers detect via data tags (no flag, no drain)
    }
  } else if (role == 2){
    ushort* p1H = hp + 131072;
    ushort* p1L = hp + 163840;
    const int bb16  = bbase + 16*bh;
    const int kq    = v*128;                 // k-quarter per wave
    const int aoffA = (bb16 + col)*512 + kq + q*8;
    float hc0 = 0.f, hc1 = 0.f, hc2 = 0.f, hc3 = 0.f;   // wave0: batches 4q+i
    for (int t = 0; t < TT; ++t){
      // -------- phase A (slack-funded): gh1 = Whh1 @ h1[t-1], full prec ----
      const uint emA = (t==0) ? 0u : ((((t-1)&1u)^1u) * TAGM);
      waitcan2(p1H + (size_t)bb16*512, p1H + (size_t)bb16*512 + 496, emA, tid);
      f32x4 aR={0,0,0,0}, aZ={0,0,0,0}, aNi={0,0,0,0}, aNh={0,0,0,0};
      {
        const uint em_ = emA;
        for(;;){
          uint4v ha0,ha1,ha2,ha3, la0,la1,la2,la3;
          LD4A(ha0, p1H, aoffA+0*32) LD4A(ha1, p1H, aoffA+1*32)
          LD4A(ha2, p1H, aoffA+2*32) LD4A(ha3, p1H, aoffA+3*32)
          LD4A(la0, p1L, aoffA+0*32) LD4A(la1, p1L, aoffA+1*32)
          LD4A(la2, p1L, aoffA+2*32) LD4A(la3, p1L, aoffA+3*32)
          VMBAR8(ha0,ha1,ha2,ha3,la0,la1,la2,la3)
          uint fo_ = 0u;
          FOLD4(ha) FOLD4(la)
          if (__all((int)(fo_ == 0u))){ RUN4(GH1) break; }
          __builtin_amdgcn_s_sleep(1);
        }
      }
      // -------- phase B (critical): gi = Wih1_hi @ h0hi[t] ----------------
      const ushort* rH = hp + ((t & 1) ^ 1)*32768;
      const uint emB = (((t>>1)&1u)^1u) * TAGM;
      waitcan2(rH + (size_t)bb16*512, rH + (size_t)bb16*512 + 496, emB, tid);
      {
        const uint em_ = emB;
        for(;;){
          uint4v ga0,ga1,ga2,ga3;
          LD4A(ga0, rH, aoffA+0*32) LD4A(ga1, rH, aoffA+1*32)
          LD4A(ga2, rH, aoffA+2*32) LD4A(ga3, rH, aoffA+3*32)
          VMBAR4(ga0,ga1,ga2,ga3)
          uint fo_ = 0u;
          FOLD4(ga)
          if (__all((int)(fo_ == 0u))){ RUN4(GI1) break; }
          __builtin_amdgcn_s_sleep(1);
        }
      }
      // -------- combine k-quarters, EW, store -----------------------------
      if (v >= 1){
        *(f32x4*)&S2.xk[v-1][l][0]  = aR;
        *(f32x4*)&S2.xk[v-1][l][4]  = aZ;
        *(f32x4*)&S2.xk[v-1][l][8]  = aNi;
        *(f32x4*)&S2.xk[v-1][l][12] = aNh;
      }
      __syncthreads();
      if (v == 0){
        const uint tg1_ = (t&1u)^1u;
        #pragma unroll
        for (int w = 0; w < 3; ++w){
          aR  += *(const f32x4*)&S2.xk[w][l][0];
          aZ  += *(const f32x4*)&S2.xk[w][l][4];
          aNi += *(const f32x4*)&S2.xk[w][l][8];
          aNh += *(const f32x4*)&S2.xk[w][l][12];
        }
        float bsR = S2.bsumR[col], bsZ = S2.bsumZ[col];
        float biN = S2.binN[col],  bhN = S2.bhnN[col];
        #define E1(i, HC) { \
          float r1 = sigm(aR[i] + bsR); \
          float z1 = sigm(aZ[i] + bsZ); \
          float n1 = tanh_f(aNi[i] + biN + r1*(aNh[i] + bhN)); \
          float h = (1.f-z1)*n1 + z1*HC; \
          HC = h; \
          uint hu_ = ((uint)bfrnd(h) & 0xFFFEu) | tg1_; \
          uint lu_ = ((uint)bfrnd(h - bf2f((ushort)hu_)) & 0xFFFEu) | tg1_; \
          STSH(p1H + (size_t)(bb16 + 4*q + (i))*512 + ng, hu_) \
          STSH(p1L + (size_t)(bb16 + 4*q + (i))*512 + ng, lu_) }
        E1(0,hc0) E1(1,hc1) E1(2,hc2) E1(3,hc3)
        #undef E1
      }
      __syncthreads();                       // xk buffer reuse fence
    }
  } else {
    const ushort* rH = hp + 131072;          // h1 hi plane ONLY (critical)
    const int bblk  = v & 1;
    const int kb    = (v >> 1)*256;
    const int aoff8 = (bbase + 16*bblk + col)*512 + kb + q*8;
    const int b0wL  = 16*bblk + 4*q;
    for (int t = 0; t < TT; ++t){
      const uint emh1 = ((t&1u)^1u) * TAGM;
      // dual canary spanning both batch halves AND both j extremes
      waitcan2(rH + (size_t)bbase*512,
               rH + (size_t)(bbase+16)*512 + 496, emh1, tid);
      f32x4 acc0={0,0,0,0};
      {
        const uint em_ = emh1;
        for(;;){
          DECL_HI8(rH)
          uint fo_ = 0u;
          FOLD8(ha)
          if (__all((int)(fo_ == 0u))){ RUN8(MS1H) break; }
          __builtin_amdgcn_s_sleep(1);
        }
      }
      if (v >= 2)
        *(f32x4*)&S3.xk[bblk][l][0] = acc0;
      __syncthreads();
      if (v < 2){
        acc0 += *(const f32x4*)&S3.xk[bblk][l][0];
        float s0 = S3.wo2v[col]*fmaxf(acc0[0] + S3.bo1v[col], 0.f);
        float s1 = S3.wo2v[col]*fmaxf(acc0[1] + S3.bo1v[col], 0.f);
        float s2 = S3.wo2v[col]*fmaxf(acc0[2] + S3.bo1v[col], 0.f);
        float s3 = S3.wo2v[col]*fmaxf(acc0[3] + S3.bo1v[col], 0.f);
        #pragma unroll
        for (int d = 1; d < 16; d <<= 1){
          s0 += __shfl_xor(s0, d);
          s1 += __shfl_xor(s1, d);
          s2 += __shfl_xor(s2, d);
          s3 += __shfl_xor(s3, d);
        }
        if (col == 0){
          const uint tgy_ = ((t>>1)&1u)^1u;
          uint* rp = (uint*)(yout + (t&1)*2048 + j*64 + bbase + b0wL);
          uint4v uv = { (__float_as_uint(s0) & ~1u) | tgy_,
                        (__float_as_uint(s1) & ~1u) | tgy_,
                        (__float_as_uint(s2) & ~1u) | tgy_,
                        (__float_as_uint(s3) & ~1u) | tgy_ };
          ST4SC(rp, uv)
        }
      }
      __syncthreads();                       // xk buffer reuse fence
    }
  }

  // ---------------- finale: drain once, then global barrier ---------------
  drain_sync();
  gbar(gslots, epoch, wg, tid, 2);
  if (wg == 0 && tid < 64){
    float s = 0.f;
    const float* yp = yout + 2048 + tid;     // parity of t=1023 is 1
    #pragma unroll
    for (int jj = 0; jj < 32; ++jj) s += ALDF(yp + jj*64);
    out[(size_t)tid*TT + 1023] = fmaxf(s + bo2v, 0.f);
  }
  {
    int g = wg*256 + tid;                    // 256 WGs x 256 thr = 65536
    if (g < 32768) out[65536 + g] = bf2f(hp[g]) + bf2f(hp[65536 + g]);
    else {
      int g2 = g - 32768;
      out[65536 + g] = bf2f(hp[131072 + g2]) + bf2f(hp[163840 + g2]);
    }
  }
}

extern "C" void kernel_launch(void* const* d_in, const int* in_sizes, int n_in,
                              void* d_out, int out_size, void* d_ws, size_t ws_size,
                              hipStream_t stream){
  const float* ctx   = (const float*)d_in[0];
  const float* Wih0  = (const float*)d_in[2];
  const float* Whh0  = (const float*)d_in[3];
  const float* bih0  = (const float*)d_in[4];
  const float* bhh0  = (const float*)d_in[5];
  const float* Wih1  = (const float*)d_in[6];
  const float* Whh1  = (const float*)d_in[7];
  const float* bih1  = (const float*)d_in[8];
  const float* bhh1  = (const float*)d_in[9];
  const float* Wo1   = (const float*)d_in[10];
  const float* bo1   = (const float*)d_in[11];
  const float* Wo2   = (const float*)d_in[12];
  const float* bo2   = (const float*)d_in[13];

  (void)in_sizes; (void)n_in; (void)out_size; (void)ws_size;

  const int smem_sz = (int)sizeof(SmemR2);   // largest overlay (162,304 B)
  (void)hipFuncSetAttribute((const void*)decoder_rnn,
                            hipFuncAttributeMaxDynamicSharedMemorySize,
                            smem_sz);

  decoder_rnn<<<NWG, NT, smem_sz, stream>>>(
      ctx, Wih0, Whh0, bih0, bhh0, Wih1, Whh1, bih1, bhh1,
      Wo1, bo1, Wo2, bo2, (float*)d_out, (float*)d_ws);
}